// Round 6
// baseline (14201.303 us; speedup 1.0000x reference)
//
#include <hip/hip_runtime.h>

// MusicVAE forward. B=256, T=128, NC=96, H=512, G=1536, NB=32, CPB=4.
// All inputs f32; all outputs f32. bf16 MFMA compute, f32 state/accumulate.
// Persistent multi-step GRU kernels with device-scope flag sync.

#define BB   256
#define TT   128
#define NCC  96
#define HDIM 512
#define GG   1536
#define NBB  32
#define CPBB 4

typedef __attribute__((ext_vector_type(4))) float f32x4;
typedef __attribute__((ext_vector_type(8))) short bf16x8;
typedef unsigned short ushort_t;

__device__ __forceinline__ unsigned short f2b(float x) {
  unsigned int u = __builtin_bit_cast(unsigned int, x);
  u += 0x7fff + ((u >> 16) & 1);
  return (unsigned short)(u >> 16);
}
__device__ __forceinline__ float b2f(unsigned short h) {
  unsigned int u = ((unsigned int)h) << 16;
  return __builtin_bit_cast(float, u);
}
__device__ __forceinline__ uint2 packA(float4 v) {
  uint2 r;
  r.x = (unsigned)f2b(v.x) | ((unsigned)f2b(v.y) << 16);
  r.y = (unsigned)f2b(v.z) | ((unsigned)f2b(v.w) << 16);
  return r;
}
__device__ __forceinline__ uint4 packA8(float4 v0, float4 v1) {
  uint4 r;
  r.x = (unsigned)f2b(v0.x) | ((unsigned)f2b(v0.y) << 16);
  r.y = (unsigned)f2b(v0.z) | ((unsigned)f2b(v0.w) << 16);
  r.z = (unsigned)f2b(v1.x) | ((unsigned)f2b(v1.y) << 16);
  r.w = (unsigned)f2b(v1.z) | ((unsigned)f2b(v1.w) << 16);
  return r;
}

__global__ void cvt_bf16_k(const float* __restrict__ s, ushort_t* __restrict__ d, int n4) {
  int i = blockIdx.x * 256 + threadIdx.x;
  if (i >= n4) return;
  float4 v = reinterpret_cast<const float4*>(s)[i];
  ushort4 o;
  o.x = f2b(v.x); o.y = f2b(v.y); o.z = f2b(v.z); o.w = f2b(v.w);
  reinterpret_cast<ushort4*>(d)[i] = o;
}

// ---------------------------------------------------------------------------
// Persistent 16-step GRU. Grid (4 rb, 32 cb, 2 dir), 256 thr.
// Whh slice resident in LDS. Group sync = 32 blocks sharing (dir, rb).
// mode 0: enc0 (A from y0b at t-mapped slot; writes y0b + f32 ping)
// mode 1: enc1 (A from bf16 ping; writes bf16 ping + f32 ping)
// gx precomputed bf16 [2][4096][1536] (bih folded).
// ---------------------------------------------------------------------------
struct PersistP {
  ushort_t* y0b;
  ushort_t* h16;
  float* hf;
  const ushort_t* gx;
  const ushort_t* whh;      // per-dir stride 786432
  const float* bhh;         // per-dir stride 1536
  int t0; int mode;
  int* flags;               // 8 ints: dir*4+rb
};

__global__ __launch_bounds__(256) void persist16_k(PersistP p)
{
  __shared__ ushort_t Wl[48][512];
  __shared__ ushort_t Al[2][64][32];
  const int tid = threadIdx.x;
  const int lane = tid & 63, wr = tid >> 6;
  const int rb = blockIdx.x, cb = blockIdx.y, dir = blockIdx.z;
  const int r0 = rb * 64, c0 = cb * 16;
  const int cLane = c0 + (lane & 15);
  const int fg = dir * 4 + rb;

  {
    const ushort_t* wd = p.whh + (size_t)dir * 786432;
#pragma unroll
    for (int it = 0; it < 12; ++it) {
      int flat = tid + it * 256;
      int gc = flat >> 6, blk = flat & 63;
      int g = gc >> 4, c = gc & 15;
      *reinterpret_cast<uint4*>(&Wl[gc][(blk ^ (c & 7)) << 3]) =
        *reinterpret_cast<const uint4*>(wd + (((size_t)(g * 512 + c0 + c)) << 9) + (blk << 3));
    }
  }
  const float bhhr = p.bhh[dir * 1536 + cLane];
  const float bhhz = p.bhh[dir * 1536 + 512 + cLane];
  const float bhhn = p.bhh[dir * 1536 + 1024 + cLane];
  const int arow = tid >> 2, ablk = tid & 3;
  const int aRdRow = wr * 16 + (lane & 15);
  const int aRdBlk = ((lane >> 4) ^ (aRdRow & 3)) << 3;
  const int ccL = lane & 15;
  __syncthreads();

  for (int s = 0; s < 16; ++s) {
    const int t = p.t0 + s;
    f32x4 aR = {}, aZ = {}, aN = {};
    if (t > 0) {
      const ushort_t* asrc;
      if (p.mode == 0) {
        int tIdx = dir ? (128 - t) : (t - 1);
        asrc = p.y0b + (size_t)(r0 + arow) * 131072 + tIdx * 1024 + dir * 512;
      } else {
        asrc = p.h16 + ((t + 1) & 1) * 262144 + dir * 131072 + (size_t)(r0 + arow) * 512;
      }
      *reinterpret_cast<uint4*>(&Al[0][arow][(ablk ^ (arow & 3)) << 3]) =
        *reinterpret_cast<const uint4*>(asrc + (ablk << 3));
      __syncthreads();
      for (int kc = 0; kc < 16; ++kc) {
        int buf = kc & 1;
        if (kc < 15) {
          *reinterpret_cast<uint4*>(&Al[buf ^ 1][arow][(ablk ^ (arow & 3)) << 3]) =
            *reinterpret_cast<const uint4*>(asrc + ((kc + 1) << 5) + (ablk << 3));
        }
        bf16x8 af = *reinterpret_cast<const bf16x8*>(&Al[buf][aRdRow][aRdBlk]);
        int blk64 = (kc << 2) + (lane >> 4);
        int wblk = (blk64 ^ (ccL & 7)) << 3;
        bf16x8 b0 = *reinterpret_cast<const bf16x8*>(&Wl[ccL][wblk]);
        bf16x8 b1 = *reinterpret_cast<const bf16x8*>(&Wl[16 + ccL][wblk]);
        bf16x8 b2 = *reinterpret_cast<const bf16x8*>(&Wl[32 + ccL][wblk]);
        aR = __builtin_amdgcn_mfma_f32_16x16x32_bf16(af, b0, aR, 0, 0, 0);
        aZ = __builtin_amdgcn_mfma_f32_16x16x32_bf16(af, b1, aZ, 0, 0, 0);
        aN = __builtin_amdgcn_mfma_f32_16x16x32_bf16(af, b2, aN, 0, 0, 0);
        __syncthreads();
      }
    }
    {
      const size_t hOff = (size_t)dir * 131072;
#pragma unroll
      for (int rg = 0; rg < 4; ++rg) {
        int r = r0 + wr * 16 + ((lane >> 4) << 2) + rg;
        const ushort_t* g = p.gx + (size_t)dir * 6291456 + (size_t)(s * 256 + r) * 1536;
        float sr = aR[rg] + b2f(g[cLane]) + bhhr;
        float sz = aZ[rg] + b2f(g[512 + cLane]) + bhhz;
        float nx = b2f(g[1024 + cLane]);
        float nh = aN[rg] + bhhn;
        float rgate = 1.f / (1.f + expf(-sr));
        float zgate = 1.f / (1.f + expf(-sz));
        float ngate = tanhf(nx + rgate * nh);
        float hp = (t == 0) ? 0.f : p.hf[((t + 1) & 1) * 262144 + hOff + (size_t)r * 512 + cLane];
        float hv = (1.f - zgate) * ngate + zgate * hp;
        p.hf[(t & 1) * 262144 + hOff + (size_t)r * 512 + cLane] = hv;
        if (p.mode == 0) {
          int ty = dir ? (127 - t) : t;
          p.y0b[(size_t)r * 131072 + ty * 1024 + dir * 512 + cLane] = f2b(hv);
        } else {
          p.h16[(t & 1) * 262144 + hOff + (size_t)r * 512 + cLane] = f2b(hv);
        }
      }
    }
    __threadfence();
    __syncthreads();
    if (tid == 0) {
      __hip_atomic_fetch_add(&p.flags[fg], 1, __ATOMIC_RELEASE, __HIP_MEMORY_SCOPE_AGENT);
      if (s < 15) {
        while (__hip_atomic_load(&p.flags[fg], __ATOMIC_ACQUIRE, __HIP_MEMORY_SCOPE_AGENT) < 32 * (t + 1)) {}
      }
    }
    __syncthreads();
  }
}

// ---------------------------------------------------------------------------
// Persistent conductor: 32 bars x (c0, c1). Grid (4 rb, 32 cb), 256 thr.
// Weights staged per cell from L2 into LDS. Group = 32 blocks per rb.
// ---------------------------------------------------------------------------
struct CondP {
  float* h0c; float* h1c;
  const float* chv;
  const float* gxc0;
  const ushort_t* whh0; const ushort_t* wih1; const ushort_t* whh1;
  const float* bhh0; const float* bih1; const float* bhh1;
  int* flags;               // 4 ints
};

#define COND_STAGE_W(WB)                                                       \
  { _Pragma("unroll")                                                          \
    for (int it = 0; it < 12; ++it) {                                          \
      int flat = tid + it * 256;                                               \
      int gc = flat >> 6, blk = flat & 63;                                     \
      int g = gc >> 4, c = gc & 15;                                            \
      *reinterpret_cast<uint4*>(&Wl[gc][(blk ^ (c & 7)) << 3]) =               \
        *reinterpret_cast<const uint4*>((WB) + (((size_t)(g * 512 + c0 + c)) << 9) + (blk << 3)); \
    } }                                                                        \
  __syncthreads();

#define COND_RUNK(ABASE, XR, XZ, XN)                                           \
  { const float* asrc = (ABASE) + (size_t)(r0 + arow) * 512;                   \
    { float4 v0 = *reinterpret_cast<const float4*>(asrc + (ablk << 3));        \
      float4 v1 = *reinterpret_cast<const float4*>(asrc + (ablk << 3) + 4);    \
      *reinterpret_cast<uint4*>(&Al[0][arow][(ablk ^ (arow & 3)) << 3]) = packA8(v0, v1); } \
    __syncthreads();                                                           \
    for (int kc = 0; kc < 16; ++kc) {                                          \
      int buf = kc & 1;                                                        \
      if (kc < 15) {                                                           \
        float4 v0 = *reinterpret_cast<const float4*>(asrc + ((kc + 1) << 5) + (ablk << 3)); \
        float4 v1 = *reinterpret_cast<const float4*>(asrc + ((kc + 1) << 5) + (ablk << 3) + 4); \
        *reinterpret_cast<uint4*>(&Al[buf ^ 1][arow][(ablk ^ (arow & 3)) << 3]) = packA8(v0, v1); \
      }                                                                        \
      bf16x8 af = *reinterpret_cast<const bf16x8*>(&Al[buf][aRdRow][aRdBlk]);  \
      int blk64 = (kc << 2) + (lane >> 4);                                     \
      int wblk = (blk64 ^ (ccL & 7)) << 3;                                     \
      bf16x8 b0 = *reinterpret_cast<const bf16x8*>(&Wl[ccL][wblk]);            \
      bf16x8 b1 = *reinterpret_cast<const bf16x8*>(&Wl[16 + ccL][wblk]);       \
      bf16x8 b2 = *reinterpret_cast<const bf16x8*>(&Wl[32 + ccL][wblk]);       \
      XR = __builtin_amdgcn_mfma_f32_16x16x32_bf16(af, b0, XR, 0, 0, 0);       \
      XZ = __builtin_amdgcn_mfma_f32_16x16x32_bf16(af, b1, XZ, 0, 0, 0);       \
      XN = __builtin_amdgcn_mfma_f32_16x16x32_bf16(af, b2, XN, 0, 0, 0);       \
      __syncthreads();                                                         \
    } }

#define COND_SYNC(CELLIDX, DOWAIT)                                             \
  __threadfence();                                                             \
  __syncthreads();                                                             \
  if (tid == 0) {                                                              \
    __hip_atomic_fetch_add(&p.flags[rb], 1, __ATOMIC_RELEASE, __HIP_MEMORY_SCOPE_AGENT); \
    if (DOWAIT) {                                                              \
      while (__hip_atomic_load(&p.flags[rb], __ATOMIC_ACQUIRE, __HIP_MEMORY_SCOPE_AGENT) < 32 * ((CELLIDX) + 1)) {} \
    }                                                                          \
  }                                                                            \
  __syncthreads();

__global__ __launch_bounds__(256) void cond_k(CondP p)
{
  __shared__ ushort_t Wl[48][512];
  __shared__ ushort_t Al[2][64][32];
  const int tid = threadIdx.x;
  const int lane = tid & 63, wr = tid >> 6;
  const int rb = blockIdx.x, cb = blockIdx.y;
  const int r0 = rb * 64, c0 = cb * 16;
  const int cLane = c0 + (lane & 15);
  const int arow = tid >> 2, ablk = tid & 3;
  const int aRdRow = wr * 16 + (lane & 15);
  const int aRdBlk = ((lane >> 4) ^ (aRdRow & 3)) << 3;
  const int ccL = lane & 15;

  const float b0r = p.bhh0[cLane], b0z = p.bhh0[512 + cLane], b0n = p.bhh0[1024 + cLane];
  const float i1r = p.bih1[cLane], i1z = p.bih1[512 + cLane], i1n = p.bih1[1024 + cLane];
  const float b1r = p.bhh1[cLane], b1z = p.bhh1[512 + cLane], b1n = p.bhh1[1024 + cLane];

  for (int bar = 0; bar < NBB; ++bar) {
    // ----- cell 0 -----
    COND_STAGE_W(p.whh0)
    const float* h0p = bar ? p.h0c + (size_t)(bar - 1) * 131072 : p.chv;
    f32x4 hR = {}, hZ = {}, hN = {};
    COND_RUNK(h0p, hR, hZ, hN)
#pragma unroll
    for (int rg = 0; rg < 4; ++rg) {
      int r = r0 + wr * 16 + ((lane >> 4) << 2) + rg;
      const float* g = p.gxc0 + (size_t)r * 1536;
      float sr = hR[rg] + g[cLane] + b0r;
      float sz = hZ[rg] + g[512 + cLane] + b0z;
      float nx = g[1024 + cLane];
      float nh = hN[rg] + b0n;
      float rgate = 1.f / (1.f + expf(-sr));
      float zgate = 1.f / (1.f + expf(-sz));
      float ngate = tanhf(nx + rgate * nh);
      float hp = h0p[(size_t)r * 512 + cLane];
      p.h0c[(size_t)bar * 131072 + (size_t)r * 512 + cLane] = (1.f - zgate) * ngate + zgate * hp;
    }
    COND_SYNC(bar * 2, 1)
    // ----- cell 1 -----
    f32x4 xR = {}, xZ = {}, xN = {};
    COND_STAGE_W(p.wih1)
    COND_RUNK(p.h0c + (size_t)bar * 131072, xR, xZ, xN)
    __syncthreads();
    COND_STAGE_W(p.whh1)
    const float* h1p = bar ? p.h1c + (size_t)(bar - 1) * 131072 : p.chv;
    f32x4 yR = {}, yZ = {}, yN = {};
    COND_RUNK(h1p, yR, yZ, yN)
#pragma unroll
    for (int rg = 0; rg < 4; ++rg) {
      int r = r0 + wr * 16 + ((lane >> 4) << 2) + rg;
      float sr = xR[rg] + yR[rg] + i1r + b1r;
      float sz = xZ[rg] + yZ[rg] + i1z + b1z;
      float nx = xN[rg] + i1n;
      float nh = yN[rg] + b1n;
      float rgate = 1.f / (1.f + expf(-sr));
      float zgate = 1.f / (1.f + expf(-sz));
      float ngate = tanhf(nx + rgate * nh);
      float hp = h1p[(size_t)r * 512 + cLane];
      p.h1c[(size_t)bar * 131072 + (size_t)r * 512 + cLane] = (1.f - zgate) * ngate + zgate * hp;
    }
    COND_SYNC(bar * 2 + 1, (bar < 31))
  }
}

// ---------------------------------------------------------------------------
// gx GEMM: C_bf16[8192][1536] = A @ W^T + bias. Rows (dir, tl, b) map to
// timestep tsrc. Tile 64x128, 512 thr, BK=32, reg-prefetch.
// AF32=1: A = in (f32, K=96); AF32=0: A = y0b (bf16, K=1024).
// ---------------------------------------------------------------------------
template<int AF32>
__global__ __launch_bounds__(512) void gx_gemm_k(
    const void* Aarg, const ushort_t* W, int ldw, int dirWStride,
    const float* bias, ushort_t* C, int t0, int K)
{
  __shared__ ushort_t As[64][40];
  __shared__ ushort_t Bs[128][40];
  const int tid = threadIdx.x;
  const int lane = tid & 63, wv = tid >> 6;
  const int wr = wv >> 2, wc = wv & 3;
  const int rBase = blockIdx.x * 64, n0 = blockIdx.y * 128;
  const int dir = rBase >> 12;
  const int arow = tid >> 3, ak = (tid & 7) * 4;
  const int bcol = tid >> 2, bk = (tid & 3) * 8;
  int r = rBase + arow;
  int tl = (r >> 8) & 15, b = r & 255;
  int tsrc = (dir == 0) ? (t0 + tl) : (127 - t0 - tl);
  const ushort_t* apB = (const ushort_t*)Aarg + (size_t)b * 131072 + (size_t)tsrc * 1024;
  const float* apF = (const float*)Aarg + (size_t)b * 12288 + (size_t)tsrc * 96;
  const ushort_t* wrow = W + (size_t)dir * dirWStride + (size_t)(n0 + bcol) * ldw;
  f32x4 acc[2][2] = {};

  uint2 aC; uint4 bC;
  if (AF32) aC = packA(*reinterpret_cast<const float4*>(apF + ak));
  else      aC = *reinterpret_cast<const uint2*>(apB + ak);
  bC = *reinterpret_cast<const uint4*>(wrow + bk);
  for (int k0 = 0; k0 < K; k0 += 32) {
    __syncthreads();
    *reinterpret_cast<uint2*>(&As[arow][ak]) = aC;
    *reinterpret_cast<uint4*>(&Bs[bcol][bk]) = bC;
    if (k0 + 32 < K) {
      if (AF32) aC = packA(*reinterpret_cast<const float4*>(apF + k0 + 32 + ak));
      else      aC = *reinterpret_cast<const uint2*>(apB + k0 + 32 + ak);
      bC = *reinterpret_cast<const uint4*>(wrow + k0 + 32 + bk);
    }
    __syncthreads();
    bf16x8 af[2], bf[2];
#pragma unroll
    for (int i = 0; i < 2; ++i)
      af[i] = *reinterpret_cast<const bf16x8*>(&As[wr * 32 + i * 16 + (lane & 15)][(lane >> 4) * 8]);
#pragma unroll
    for (int j = 0; j < 2; ++j)
      bf[j] = *reinterpret_cast<const bf16x8*>(&Bs[wc * 32 + j * 16 + (lane & 15)][(lane >> 4) * 8]);
#pragma unroll
    for (int i = 0; i < 2; ++i)
#pragma unroll
      for (int j = 0; j < 2; ++j)
        acc[i][j] = __builtin_amdgcn_mfma_f32_16x16x32_bf16(af[i], bf[j], acc[i][j], 0, 0, 0);
  }
#pragma unroll
  for (int i = 0; i < 2; ++i)
#pragma unroll
    for (int j = 0; j < 2; ++j)
#pragma unroll
      for (int rg = 0; rg < 4; ++rg) {
        int rr = rBase + wr * 32 + i * 16 + ((lane >> 4) << 2) + rg;
        int cc = n0 + wc * 32 + j * 16 + (lane & 15);
        C[(size_t)rr * 1536 + cc] = f2b(acc[i][j][rg] + bias[dir * 1536 + cc]);
      }
}

// ---------------------------------------------------------------------------
// Decoder GRU step (32x64 tile, reg-prefetch) — unchanged from round 5.
// ---------------------------------------------------------------------------
struct GruP {
  const float* h_prev; int hs; int hz;
  const ushort_t* Whh;
  const float* x0f; const ushort_t* x0b; int x0s;
  const ushort_t* W0; int w0ld; int K0;
  const float* x1f; int x1sp; const ushort_t* W1; int w1ld; int K1;
  const float* gxf;
  const ushort_t* gxb; int gxros;
  const float* bih; const float* bhh;
  float* h_out; int os;
  ushort_t* h_out2; int o2s;
};
struct GruP2 { GruP d[2]; };

#define LB3(WP, WLD_, G_, KOFF) \
  (*reinterpret_cast<const uint4*>((WP) + (size_t)((G_) * HDIM + c0 + bn) * (size_t)(WLD_) + (KOFF) + bk))

#define AL_H(KOFF, DST)  DST = packA(*reinterpret_cast<const float4*>(p.h_prev + (size_t)(r0 + arow) * p.hs + (KOFF) + ak));
#define AL_X0F(KOFF, DST) DST = packA(*reinterpret_cast<const float4*>(p.x0f + (size_t)(r0 + arow) * p.x0s + (KOFF) + ak));
#define AL_X0B(KOFF, DST) DST = *reinterpret_cast<const uint2*>(p.x0b + (size_t)(r0 + arow) * p.x0s + (KOFF) + ak);
#define AL_CH(KOFF, DST) { int rr_ = r0 + arow; \
  DST = packA(*reinterpret_cast<const float4*>(p.x1f + (size_t)(rr_ & 255) * 12288 + (rr_ >> 8) * 384 + p.x1sp * 96 + (KOFF) + ak)); }

#define GRU_PHASE(KLEN, ALOAD, WP, WLD_, ACCN)                                 \
  { uint2 aC; uint4 b0c, b1c, b2c;                                             \
    ALOAD(0, aC)                                                               \
    b0c = LB3(WP, WLD_, 0, 0); b1c = LB3(WP, WLD_, 1, 0); b2c = LB3(WP, WLD_, 2, 0); \
    for (int k0 = 0; k0 < (KLEN); k0 += 32) {                                  \
      __syncthreads();                                                         \
      *reinterpret_cast<uint2*>(&Xs[arow][ak]) = aC;                           \
      *reinterpret_cast<uint4*>(&Bs[0][bn][bk]) = b0c;                         \
      *reinterpret_cast<uint4*>(&Bs[1][bn][bk]) = b1c;                         \
      *reinterpret_cast<uint4*>(&Bs[2][bn][bk]) = b2c;                         \
      if (k0 + 32 < (KLEN)) {                                                  \
        ALOAD(k0 + 32, aC)                                                     \
        b0c = LB3(WP, WLD_, 0, k0 + 32); b1c = LB3(WP, WLD_, 1, k0 + 32); b2c = LB3(WP, WLD_, 2, k0 + 32); \
      }                                                                        \
      __syncthreads();                                                         \
      bf16x8 afr = *reinterpret_cast<const bf16x8*>(&Xs[wr * 16 + (lane & 15)][(lane >> 4) * 8]); \
      _Pragma("unroll")                                                        \
      for (int j = 0; j < 2; ++j) {                                            \
        const int bc = wc * 32 + j * 16 + (lane & 15);                         \
        bf16x8 f0 = *reinterpret_cast<const bf16x8*>(&Bs[0][bc][(lane >> 4) * 8]); \
        bf16x8 f1 = *reinterpret_cast<const bf16x8*>(&Bs[1][bc][(lane >> 4) * 8]); \
        bf16x8 f2 = *reinterpret_cast<const bf16x8*>(&Bs[2][bc][(lane >> 4) * 8]); \
        aR[j] = __builtin_amdgcn_mfma_f32_16x16x32_bf16(afr, f0, aR[j], 0, 0, 0); \
        aZ[j] = __builtin_amdgcn_mfma_f32_16x16x32_bf16(afr, f1, aZ[j], 0, 0, 0); \
        ACCN[j] = __builtin_amdgcn_mfma_f32_16x16x32_bf16(afr, f2, ACCN[j], 0, 0, 0); \
      }                                                                        \
    } }

__global__ __launch_bounds__(256) void gru_k(GruP2 pp)
{
  const GruP p = pp.d[blockIdx.z];
  __shared__ ushort_t Xs[32][40];
  __shared__ ushort_t Bs[3][64][40];
  const int tid = threadIdx.x;
  const int lane = tid & 63, wv = tid >> 6;
  const int wr = wv >> 1, wc = wv & 1;
  const int r0 = blockIdx.x * 32, c0 = blockIdx.y * 64;
  const int arow = tid >> 3, ak = (tid & 7) * 4;
  const int bn = tid >> 2, bk = (tid & 3) * 8;
  f32x4 aR[2] = {}, aZ[2] = {}, aNX[2] = {}, aNH[2] = {};

  if (!p.hz) { GRU_PHASE(HDIM, AL_H, p.Whh, HDIM, aNH) }
  if (p.K0 > 0) {
    if (p.x0b) { GRU_PHASE(p.K0, AL_X0B, p.W0, p.w0ld, aNX) }
    else       { GRU_PHASE(p.K0, AL_X0F, p.W0, p.w0ld, aNX) }
  }
  if (p.K1 > 0) { GRU_PHASE(p.K1, AL_CH, p.W1, p.w1ld, aNX) }

#pragma unroll
  for (int j = 0; j < 2; ++j) {
#pragma unroll
    for (int rg = 0; rg < 4; ++rg) {
      int r = r0 + wr * 16 + ((lane >> 4) << 2) + rg;
      int c = c0 + wc * 32 + j * 16 + (lane & 15);
      float sr = aR[j][rg] + p.bhh[c];
      float sz = aZ[j][rg] + p.bhh[HDIM + c];
      float nx = aNX[j][rg];
      float nh = aNH[j][rg] + p.bhh[2 * HDIM + c];
      if (p.bih) { sr += p.bih[c]; sz += p.bih[HDIM + c]; nx += p.bih[2 * HDIM + c]; }
      if (p.gxf) {
        const float* g = p.gxf + (size_t)r * GG;
        sr += g[c]; sz += g[HDIM + c]; nx += g[2 * HDIM + c];
      }
      float rgate = 1.f / (1.f + expf(-sr));
      float zgate = 1.f / (1.f + expf(-sz));
      float ngate = tanhf(nx + rgate * nh);
      float hp = p.hz ? 0.f : p.h_prev[(size_t)r * p.hs + c];
      float hv = (1.f - zgate) * ngate + zgate * hp;
      p.h_out[(size_t)r * p.os + c] = hv;
      if (p.h_out2) p.h_out2[(size_t)r * p.o2s + c] = f2b(hv);
    }
  }
}

// ---------------------------------------------------------------------------
// Generic MFMA GEMM (f32 A, f32 W cvt on the fly), 32x64 tile — unchanged.
// ---------------------------------------------------------------------------
__global__ __launch_bounds__(256) void mfma_gemm_k(
    const float* __restrict__ A, int lda,
    const float* __restrict__ W, int ldw,
    const float* __restrict__ bias,
    float* __restrict__ C, int ldc, int N, int K)
{
  __shared__ ushort_t As[32][40];
  __shared__ ushort_t Bs[64][40];
  const int tid = threadIdx.x;
  const int lane = tid & 63, wv = tid >> 6;
  const int wr = wv >> 1, wc = wv & 1;
  const int r0 = blockIdx.x * 32, c0 = blockIdx.y * 64;
  const int arow = tid >> 3, ak = (tid & 7) * 4;
  const int bn = tid >> 2, bk = (tid & 3) * 8;
  f32x4 acc[2] = {};
  const int nOk = (c0 + bn) < N;
  const float* wrow = W + (size_t)(nOk ? (c0 + bn) : 0) * ldw;

  uint2 aC = packA(*reinterpret_cast<const float4*>(A + (size_t)(r0 + arow) * lda + ak));
  uint4 bC;
  {
    float4 v0 = *reinterpret_cast<const float4*>(wrow + bk);
    float4 v1 = *reinterpret_cast<const float4*>(wrow + bk + 4);
    bC = packA8(v0, v1);
  }
  for (int k0 = 0; k0 < K; k0 += 32) {
    __syncthreads();
    *reinterpret_cast<uint2*>(&As[arow][ak]) = aC;
    if (nOk) *reinterpret_cast<uint4*>(&Bs[bn][bk]) = bC;
    else { uint4 z; z.x = z.y = z.z = z.w = 0; *reinterpret_cast<uint4*>(&Bs[bn][bk]) = z; }
    if (k0 + 32 < K) {
      aC = packA(*reinterpret_cast<const float4*>(A + (size_t)(r0 + arow) * lda + k0 + 32 + ak));
      float4 v0 = *reinterpret_cast<const float4*>(wrow + k0 + 32 + bk);
      float4 v1 = *reinterpret_cast<const float4*>(wrow + k0 + 32 + bk + 4);
      bC = packA8(v0, v1);
    }
    __syncthreads();
    bf16x8 afr = *reinterpret_cast<const bf16x8*>(&As[wr * 16 + (lane & 15)][(lane >> 4) * 8]);
#pragma unroll
    for (int j = 0; j < 2; ++j) {
      bf16x8 bfr = *reinterpret_cast<const bf16x8*>(&Bs[wc * 32 + j * 16 + (lane & 15)][(lane >> 4) * 8]);
      acc[j] = __builtin_amdgcn_mfma_f32_16x16x32_bf16(afr, bfr, acc[j], 0, 0, 0);
    }
  }
#pragma unroll
  for (int j = 0; j < 2; ++j)
#pragma unroll
    for (int rg = 0; rg < 4; ++rg) {
      int r = r0 + wr * 16 + ((lane >> 4) << 2) + rg;
      int c = c0 + wc * 32 + j * 16 + (lane & 15);
      if (c < N) C[(size_t)r * ldc + c] = acc[j][rg] + (bias ? bias[c] : 0.f);
    }
}

// ---------------------------------------------------------------------------
// Small elementwise kernels
// ---------------------------------------------------------------------------
__global__ void gather_hidden_k(const ushort_t* __restrict__ y0b,
                                const float* __restrict__ h1f,
                                const float* __restrict__ h1b,
                                float* __restrict__ hidden)
{
  int i = blockIdx.x * 256 + threadIdx.x;
  if (i >= BB * 4 * HDIM) return;
  int b = i >> 11, j = i & 2047;
  float v;
  if (j < 512)       v = b2f(y0b[(size_t)b * 131072 + 127 * 1024 + j]);
  else if (j < 1024) v = b2f(y0b[(size_t)b * 131072 + j]);
  else if (j < 1536) v = h1f[b * 512 + (j - 1024)];
  else               v = h1b[b * 512 + (j - 1536)];
  hidden[i] = v;
}

__global__ void z_k(const float* __restrict__ mu, const float* __restrict__ lv,
                    const float* __restrict__ eps, float* __restrict__ z,
                    float* __restrict__ out_mu, float* __restrict__ out_lv)
{
  int i = blockIdx.x * 256 + threadIdx.x;
  if (i >= BB * HDIM) return;
  float m = mu[i], l = lv[i];
  z[i] = eps[i] * expf(0.5f * l) + m;
  out_mu[i] = m;
  out_lv[i] = l;
}

__global__ void softmax_k(const float* __restrict__ logits,
                          float* __restrict__ out_sm,
                          float* __restrict__ out_lsm)
{
  int q = blockIdx.x;
  int lane = threadIdx.x;
  const float* row = logits + (size_t)q * 96;
  float v0 = row[lane];
  float v1 = (lane < 32) ? row[lane + 64] : -1e30f;
  float m = fmaxf(v0, v1);
#pragma unroll
  for (int o = 32; o; o >>= 1) m = fmaxf(m, __shfl_xor(m, o));
  float e0 = expf(v0 - m);
  float e1 = (lane < 32) ? expf(v1 - m) : 0.f;
  float s = e0 + e1;
#pragma unroll
  for (int o = 32; o; o >>= 1) s += __shfl_xor(s, o);
  float inv = 1.f / s, ls = logf(s);
  int b = (q >> 2) & 255;
  int t = (q >> 10) * 4 + (q & 3);
  size_t base = (size_t)b * TT * 96 + (size_t)t * 96;
  out_sm[base + lane]  = e0 * inv;
  out_lsm[base + lane] = v0 - m - ls;
  if (lane < 32) {
    out_sm[base + lane + 64]  = e1 * inv;
    out_lsm[base + lane + 64] = v1 - m - ls;
  }
}

__global__ void echo_k(const float* __restrict__ in, float* __restrict__ out)
{
  int i = blockIdx.x * 256 + threadIdx.x;
  if (i < BB * TT * NCC) out[i] = in[i];
}

// ---------------------------------------------------------------------------
extern "C" void kernel_launch(void* const* d_in, const int* in_sizes, int n_in,
                              void* d_out, int out_size, void* d_ws, size_t ws_size,
                              hipStream_t stream)
{
  const float* in        = (const float*)d_in[0];
  const float* eps       = (const float*)d_in[2];
  const float* enc0_Wih  = (const float*)d_in[3];
  const float* enc0_Whh  = (const float*)d_in[4];
  const float* enc0_bih  = (const float*)d_in[5];
  const float* enc0_bhh  = (const float*)d_in[6];
  const float* enc1_Wih  = (const float*)d_in[7];
  const float* enc1_Whh  = (const float*)d_in[8];
  const float* enc1_bih  = (const float*)d_in[9];
  const float* enc1_bhh  = (const float*)d_in[10];
  const float* con0_Wih  = (const float*)d_in[11];
  const float* con0_Whh  = (const float*)d_in[12];
  const float* con0_bih  = (const float*)d_in[13];
  const float* con0_bhh  = (const float*)d_in[14];
  const float* con1_Wih  = (const float*)d_in[15];
  const float* con1_Whh  = (const float*)d_in[16];
  const float* con1_bih  = (const float*)d_in[17];
  const float* con1_bhh  = (const float*)d_in[18];
  const float* dec0_Wih  = (const float*)d_in[19];
  const float* dec0_Whh  = (const float*)d_in[20];
  const float* dec0_bih  = (const float*)d_in[21];
  const float* dec0_bhh  = (const float*)d_in[22];
  const float* dec1_Wih  = (const float*)d_in[23];
  const float* dec1_Whh  = (const float*)d_in[24];
  const float* dec1_bih  = (const float*)d_in[25];
  const float* dec1_bhh  = (const float*)d_in[26];
  const float* W_mu      = (const float*)d_in[27];
  const float* b_mu      = (const float*)d_in[28];
  const float* W_lv      = (const float*)d_in[29];
  const float* b_lv      = (const float*)d_in[30];
  const float* W_ci      = (const float*)d_in[31];
  const float* b_ci      = (const float*)d_in[32];
  const float* W_ch      = (const float*)d_in[33];
  const float* b_ch      = (const float*)d_in[34];
  const float* W_out     = (const float*)d_in[35];
  const float* b_out     = (const float*)d_in[36];

  // ---- workspace layout (f32 slots; total 33,540,096 < 33,554,432) ---------
  float* ws = (float*)d_ws;
  ushort_t* y0b  = (ushort_t*)ws;                         // [256][128][1024] bf16 (64 MiB)
  ushort_t* gxAll = (ushort_t*)(ws + 16777216);           // [2][4096][1536] bf16 (25.2 MB)
  // decoder-phase aliases:
  float* h0c   = ws;                                      // [32][256][512]
  float* h1c   = ws + 4194304;
  float* d0p[2] = { ws + 8388608,  ws + 12582912 };
  float* d1p[2] = { ws + 16777216, ws + 20971520 };       // ends 25,165,824
  // persistent state
  float* hfping = ws + 25165824;                          // [2][2][256][512] f32
  ushort_t* h16ping = (ushort_t*)(ws + 25690112);         // [2][2][256][512] bf16
  float* hidden = ws + 25952256;                          // [256][2048]
  float* mu_f  = ws + 26476544;
  float* lv_f  = ws + 26607616;
  float* zz    = ws + 26738688;
  float* ci    = ws + 26869760;
  float* chv   = ws + 26894336;
  float* gx_c0 = ws + 27025408;                           // [256][1536] ends 27,418,624
  int*   flags = (int*)(ws + 27418624);                   // 1024 ints
  ushort_t* Wb = (ushort_t*)(ws + 27420672);              // 12,238,848 bf16

  ushort_t* wb_e0_Wih = Wb;
  ushort_t* wb_e0_Whh = Wb + 294912;
  ushort_t* wb_e1_Wih = Wb + 1867776;
  ushort_t* wb_e1_Whh = Wb + 5013504;
  ushort_t* wb_c0_Whh = Wb + 6586368;
  ushort_t* wb_c1_Wih = Wb + 7372800;
  ushort_t* wb_c1_Whh = Wb + 8159232;
  ushort_t* wb_d0_Wih = Wb + 8945664;
  ushort_t* wb_d0_Whh = Wb + 9879552;
  ushort_t* wb_d1_Wih = Wb + 10665984;
  ushort_t* wb_d1_Whh = Wb + 11452416;

  float* outp   = (float*)d_out;
  float* out_sm = outp;
  float* out_ls = outp + 3145728;
  float* out_mu = outp + 6291456;
  float* out_lv = outp + 6422528;
  float* out_ec = outp + 6553600;
  float* logits_q = out_ec;                               // [8192 x 384] scratch in echo region

  auto cvt = [&](const float* s, ushort_t* d, int n) {
    cvt_bf16_k<<<(n / 4 + 255) / 256, 256, 0, stream>>>(s, d, n / 4);
  };
  auto gemmM = [&](const float* A, int lda, const float* W, int ldw, const float* bias,
                   float* C, int ldc, int M, int N, int K) {
    mfma_gemm_k<<<dim3(M / 32, (N + 63) / 64), 256, 0, stream>>>(A, lda, W, ldw, bias, C, ldc, N, K);
  };
  auto gru1 = [&](const GruP& a, int rows) {
    GruP2 q; q.d[0] = a; q.d[1] = a;
    gru_k<<<dim3(rows / 32, 8, 1), 256, 0, stream>>>(q);
  };

  hipMemsetAsync(flags, 0, 4096, stream);

  // ---------------- weight conversion ---------------------------------------
  cvt(enc0_Wih, wb_e0_Wih, 294912);
  cvt(enc0_Whh, wb_e0_Whh, 1572864);
  cvt(enc1_Wih, wb_e1_Wih, 3145728);
  cvt(enc1_Whh, wb_e1_Whh, 1572864);
  cvt(con0_Whh, wb_c0_Whh, 786432);
  cvt(con1_Wih, wb_c1_Wih, 786432);
  cvt(con1_Whh, wb_c1_Whh, 786432);
  cvt(dec0_Wih, wb_d0_Wih, 933888);
  cvt(dec0_Whh, wb_d0_Whh, 786432);
  cvt(dec1_Wih, wb_d1_Wih, 786432);
  cvt(dec1_Whh, wb_d1_Whh, 786432);

  // ---------------- encoder layer 0 (8 chunks of 16 steps) -------------------
  for (int ch = 0; ch < 8; ++ch) {
    int t0 = ch * 16;
    gx_gemm_k<1><<<dim3(128, 12), 512, 0, stream>>>(
        (const void*)in, wb_e0_Wih, 96, 147456, enc0_bih, gxAll, t0, 96);
    PersistP p = {};
    p.y0b = y0b; p.h16 = h16ping; p.hf = hfping;
    p.gx = gxAll; p.whh = wb_e0_Whh; p.bhh = enc0_bhh;
    p.t0 = t0; p.mode = 0; p.flags = flags;
    persist16_k<<<dim3(4, 32, 2), 256, 0, stream>>>(p);
  }

  // ---------------- encoder layer 1 (8 chunks) -------------------------------
  for (int ch = 0; ch < 8; ++ch) {
    int t0 = ch * 16;
    gx_gemm_k<0><<<dim3(128, 12), 512, 0, stream>>>(
        (const void*)y0b, wb_e1_Wih, 1024, 1572864, enc1_bih, gxAll, t0, 1024);
    PersistP p = {};
    p.y0b = y0b; p.h16 = h16ping; p.hf = hfping;
    p.gx = gxAll; p.whh = wb_e1_Whh; p.bhh = enc1_bhh;
    p.t0 = t0; p.mode = 1; p.flags = flags + 8;
    persist16_k<<<dim3(4, 32, 2), 256, 0, stream>>>(p);
  }

  // ---------------- latent ----------------------------------------------------
  gather_hidden_k<<<2048, 256, 0, stream>>>(y0b, hfping + 262144, hfping + 262144 + 131072, hidden);
  gemmM(hidden, 2048, W_mu, 2048, b_mu, mu_f, 512, BB, 512, 2048);
  gemmM(hidden, 2048, W_lv, 2048, b_lv, lv_f, 512, BB, 512, 2048);
  z_k<<<512, 256, 0, stream>>>(mu_f, lv_f, eps, zz, out_mu, out_lv);
  gemmM(zz, 512, W_ci, 512, b_ci, ci, 96, BB, 96, 512);
  gemmM(zz, 512, W_ch, 512, b_ch, chv, 512, BB, 512, 512);
  gemmM(ci, 96, con0_Wih, 96, con0_bih, gx_c0, GG, BB, GG, 96);

  // ---------------- conductor (persistent, 64 cells) --------------------------
  {
    CondP c = {};
    c.h0c = h0c; c.h1c = h1c; c.chv = chv; c.gxc0 = gx_c0;
    c.whh0 = wb_c0_Whh; c.wih1 = wb_c1_Wih; c.whh1 = wb_c1_Whh;
    c.bhh0 = con0_bhh; c.bih1 = con1_bih; c.bhh1 = con1_bhh;
    c.flags = flags + 16;
    cond_k<<<dim3(4, 32), 256, 0, stream>>>(c);
  }

  // ---------------- decoder: 8192 rows, 4 steps -------------------------------
  const int R = NBB * BB;
  for (int s = 0; s < CPBB; ++s) {
    GruP d0 = {};
    d0.h_prev = (s == 0) ? h0c : d0p[(s - 1) & 1]; d0.hs = 512;
    d0.x0f = h1c; d0.x0s = 512; d0.W0 = wb_d0_Wih; d0.w0ld = 608; d0.K0 = 512;
    d0.x1f = in; d0.x1sp = s; d0.W1 = wb_d0_Wih + 512; d0.w1ld = 608; d0.K1 = 96;
    d0.Whh = wb_d0_Whh; d0.bih = dec0_bih; d0.bhh = dec0_bhh;
    d0.h_out = d0p[s & 1]; d0.os = 512;
    gru1(d0, R);
    GruP d1 = {};
    d1.h_prev = (s == 0) ? h1c : d1p[(s - 1) & 1]; d1.hs = 512;
    d1.x0f = d0p[s & 1]; d1.x0s = 512; d1.W0 = wb_d1_Wih; d1.w0ld = 512; d1.K0 = 512;
    d1.Whh = wb_d1_Whh; d1.bih = dec1_bih; d1.bhh = dec1_bhh;
    d1.h_out = d1p[s & 1]; d1.os = 512;
    gru1(d1, R);
    gemmM(d1p[s & 1], 512, W_out, 512, b_out, logits_q + (size_t)s * 96, 384, R, 96, 512);
  }

  // ---------------- softmax + echo --------------------------------------------
  softmax_k<<<NBB * BB * CPBB, 64, 0, stream>>>(logits_q, out_sm, out_ls);
  echo_k<<<12288, 256, 0, stream>>>(in, out_ec);
}

// Round 7
// 10395.490 us; speedup vs baseline: 1.3661x; 1.3661x over previous
//
#include <hip/hip_runtime.h>

// MusicVAE forward. B=256, T=128, NC=96, H=512, G=1536, NB=32, CPB=4.
// All inputs f32; all outputs f32. bf16 MFMA compute, f32 state/accumulate.
// Structure: per-step launches (cheap coherence); gx projections hoisted.

#define BB   256
#define TT   128
#define NCC  96
#define HDIM 512
#define GG   1536
#define NBB  32
#define CPBB 4

typedef __attribute__((ext_vector_type(4))) float f32x4;
typedef __attribute__((ext_vector_type(8))) short bf16x8;
typedef unsigned short ushort_t;

__device__ __forceinline__ unsigned short f2b(float x) {
  unsigned int u = __builtin_bit_cast(unsigned int, x);
  u += 0x7fff + ((u >> 16) & 1);
  return (unsigned short)(u >> 16);
}
__device__ __forceinline__ float b2f(unsigned short h) {
  unsigned int u = ((unsigned int)h) << 16;
  return __builtin_bit_cast(float, u);
}
__device__ __forceinline__ uint2 packA(float4 v) {
  uint2 r;
  r.x = (unsigned)f2b(v.x) | ((unsigned)f2b(v.y) << 16);
  r.y = (unsigned)f2b(v.z) | ((unsigned)f2b(v.w) << 16);
  return r;
}
__device__ __forceinline__ uint4 packA8(float4 v0, float4 v1) {
  uint4 r;
  r.x = (unsigned)f2b(v0.x) | ((unsigned)f2b(v0.y) << 16);
  r.y = (unsigned)f2b(v0.z) | ((unsigned)f2b(v0.w) << 16);
  r.z = (unsigned)f2b(v1.x) | ((unsigned)f2b(v1.y) << 16);
  r.w = (unsigned)f2b(v1.z) | ((unsigned)f2b(v1.w) << 16);
  return r;
}

__global__ void cvt_bf16_k(const float* __restrict__ s, ushort_t* __restrict__ d, int n4) {
  int i = blockIdx.x * 256 + threadIdx.x;
  if (i >= n4) return;
  float4 v = reinterpret_cast<const float4*>(s)[i];
  ushort4 o;
  o.x = f2b(v.x); o.y = f2b(v.y); o.z = f2b(v.z); o.w = f2b(v.w);
  reinterpret_cast<ushort4*>(d)[i] = o;
}

// ---------------------------------------------------------------------------
// step_k: GRU step with all x-contributions precomputed in gx.
// Computes h_new = GRU(h_prev @ Whh (+bhh), gx). Tile 32 rows x 64 cols,
// 256 thr (4 waves), BK=64 (two 32-chunks per barrier pair), reg prefetch.
// ---------------------------------------------------------------------------
struct StepP {
  const float* h_prev; int hz;
  const ushort_t* whh;      // [1536][512] bf16
  const float* bhh;         // [1536]
  const ushort_t* gxb; int gxros;  // bf16 gx rows (gxros+r), stride 1536 (bih folded)
  const float* gxf;                // f32 gx rows r, stride 1536 (bih folded)
  float* h_out;
  ushort_t* y0o; int y0st;  // optional bf16 mirror
};
struct StepP2 { StepP d[2]; };

__global__ __launch_bounds__(256) void step_k(StepP2 pp)
{
  const StepP p = pp.d[blockIdx.z];
  __shared__ ushort_t As[2][32][40];
  __shared__ ushort_t Bs[3][2][64][40];
  const int tid = threadIdx.x;
  const int lane = tid & 63, wv = tid >> 6;
  const int wr = wv >> 1, wc = wv & 1;
  const int r0 = blockIdx.x * 32, c0 = blockIdx.y * 64;
  const int arow = tid >> 3, ak = (tid & 7) * 4;
  const int bn = tid >> 2, bk = (tid & 3) * 8;
  f32x4 aR[2] = {}, aZ[2] = {}, aN[2] = {};

  if (!p.hz) {
    const float* asrc = p.h_prev + (size_t)(r0 + arow) * 512;
    const ushort_t* w0 = p.whh + (size_t)(c0 + bn) * 512;
    uint2 a0 = packA(*reinterpret_cast<const float4*>(asrc + ak));
    uint2 a1 = packA(*reinterpret_cast<const float4*>(asrc + 32 + ak));
    uint4 bpre[3][2];
#pragma unroll
    for (int g = 0; g < 3; ++g) {
      bpre[g][0] = *reinterpret_cast<const uint4*>(w0 + (size_t)g * 262144 + bk);
      bpre[g][1] = *reinterpret_cast<const uint4*>(w0 + (size_t)g * 262144 + 32 + bk);
    }
    for (int k0 = 0; k0 < 512; k0 += 64) {
      __syncthreads();
      *reinterpret_cast<uint2*>(&As[0][arow][ak]) = a0;
      *reinterpret_cast<uint2*>(&As[1][arow][ak]) = a1;
#pragma unroll
      for (int g = 0; g < 3; ++g) {
        *reinterpret_cast<uint4*>(&Bs[g][0][bn][bk]) = bpre[g][0];
        *reinterpret_cast<uint4*>(&Bs[g][1][bn][bk]) = bpre[g][1];
      }
      if (k0 + 64 < 512) {
        a0 = packA(*reinterpret_cast<const float4*>(asrc + k0 + 64 + ak));
        a1 = packA(*reinterpret_cast<const float4*>(asrc + k0 + 96 + ak));
#pragma unroll
        for (int g = 0; g < 3; ++g) {
          bpre[g][0] = *reinterpret_cast<const uint4*>(w0 + (size_t)g * 262144 + k0 + 64 + bk);
          bpre[g][1] = *reinterpret_cast<const uint4*>(w0 + (size_t)g * 262144 + k0 + 96 + bk);
        }
      }
      __syncthreads();
#pragma unroll
      for (int h = 0; h < 2; ++h) {
        bf16x8 af = *reinterpret_cast<const bf16x8*>(&As[h][wr * 16 + (lane & 15)][(lane >> 4) * 8]);
#pragma unroll
        for (int j = 0; j < 2; ++j) {
          const int bc = wc * 32 + j * 16 + (lane & 15);
          bf16x8 f0 = *reinterpret_cast<const bf16x8*>(&Bs[0][h][bc][(lane >> 4) * 8]);
          bf16x8 f1 = *reinterpret_cast<const bf16x8*>(&Bs[1][h][bc][(lane >> 4) * 8]);
          bf16x8 f2 = *reinterpret_cast<const bf16x8*>(&Bs[2][h][bc][(lane >> 4) * 8]);
          aR[j] = __builtin_amdgcn_mfma_f32_16x16x32_bf16(af, f0, aR[j], 0, 0, 0);
          aZ[j] = __builtin_amdgcn_mfma_f32_16x16x32_bf16(af, f1, aZ[j], 0, 0, 0);
          aN[j] = __builtin_amdgcn_mfma_f32_16x16x32_bf16(af, f2, aN[j], 0, 0, 0);
        }
      }
    }
  }
#pragma unroll
  for (int j = 0; j < 2; ++j) {
#pragma unroll
    for (int rg = 0; rg < 4; ++rg) {
      int r = r0 + wr * 16 + ((lane >> 4) << 2) + rg;
      int c = c0 + wc * 32 + j * 16 + (lane & 15);
      float sr = aR[j][rg] + p.bhh[c];
      float sz = aZ[j][rg] + p.bhh[HDIM + c];
      float nh = aN[j][rg] + p.bhh[2 * HDIM + c];
      float gr, gz, gn;
      if (p.gxb) {
        const ushort_t* g = p.gxb + (size_t)(p.gxros + r) * 1536;
        gr = b2f(g[c]); gz = b2f(g[512 + c]); gn = b2f(g[1024 + c]);
      } else {
        const float* g = p.gxf + (size_t)r * 1536;
        gr = g[c]; gz = g[512 + c]; gn = g[1024 + c];
      }
      float rgate = 1.f / (1.f + expf(-(gr + sr)));
      float zgate = 1.f / (1.f + expf(-(gz + sz)));
      float ngate = tanhf(gn + rgate * nh);
      float hp = p.hz ? 0.f : p.h_prev[(size_t)r * 512 + c];
      float hv = (1.f - zgate) * ngate + zgate * hp;
      p.h_out[(size_t)r * 512 + c] = hv;
      if (p.y0o) p.y0o[(size_t)r * p.y0st + c] = f2b(hv);
    }
  }
}

// ---------------------------------------------------------------------------
// gx GEMM: C_bf16[8192][1536] = A @ W^T + bias. Rows (dir, tl, b) map to
// timestep tsrc. Tile 64x128, 512 thr, BK=32, reg-prefetch.
// AF32=1: A = in (f32, K=96); AF32=0: A = y0b (bf16, K=1024).
// ---------------------------------------------------------------------------
template<int AF32>
__global__ __launch_bounds__(512) void gx_gemm_k(
    const void* Aarg, const ushort_t* W, int ldw, int dirWStride,
    const float* bias, ushort_t* C, int t0, int K)
{
  __shared__ ushort_t As[64][40];
  __shared__ ushort_t Bs[128][40];
  const int tid = threadIdx.x;
  const int lane = tid & 63, wv = tid >> 6;
  const int wr = wv >> 2, wc = wv & 3;
  const int rBase = blockIdx.x * 64, n0 = blockIdx.y * 128;
  const int dir = rBase >> 12;
  const int arow = tid >> 3, ak = (tid & 7) * 4;
  const int bcol = tid >> 2, bk = (tid & 3) * 8;
  int r = rBase + arow;
  int tl = (r >> 8) & 15, b = r & 255;
  int tsrc = (dir == 0) ? (t0 + tl) : (127 - t0 - tl);
  const ushort_t* apB = (const ushort_t*)Aarg + (size_t)b * 131072 + (size_t)tsrc * 1024;
  const float* apF = (const float*)Aarg + (size_t)b * 12288 + (size_t)tsrc * 96;
  const ushort_t* wrow = W + (size_t)dir * dirWStride + (size_t)(n0 + bcol) * ldw;
  f32x4 acc[2][2] = {};

  uint2 aC; uint4 bC;
  if (AF32) aC = packA(*reinterpret_cast<const float4*>(apF + ak));
  else      aC = *reinterpret_cast<const uint2*>(apB + ak);
  bC = *reinterpret_cast<const uint4*>(wrow + bk);
  for (int k0 = 0; k0 < K; k0 += 32) {
    __syncthreads();
    *reinterpret_cast<uint2*>(&As[arow][ak]) = aC;
    *reinterpret_cast<uint4*>(&Bs[bcol][bk]) = bC;
    if (k0 + 32 < K) {
      if (AF32) aC = packA(*reinterpret_cast<const float4*>(apF + k0 + 32 + ak));
      else      aC = *reinterpret_cast<const uint2*>(apB + k0 + 32 + ak);
      bC = *reinterpret_cast<const uint4*>(wrow + k0 + 32 + bk);
    }
    __syncthreads();
    bf16x8 af[2], bf[2];
#pragma unroll
    for (int i = 0; i < 2; ++i)
      af[i] = *reinterpret_cast<const bf16x8*>(&As[wr * 32 + i * 16 + (lane & 15)][(lane >> 4) * 8]);
#pragma unroll
    for (int j = 0; j < 2; ++j)
      bf[j] = *reinterpret_cast<const bf16x8*>(&Bs[wc * 32 + j * 16 + (lane & 15)][(lane >> 4) * 8]);
#pragma unroll
    for (int i = 0; i < 2; ++i)
#pragma unroll
      for (int j = 0; j < 2; ++j)
        acc[i][j] = __builtin_amdgcn_mfma_f32_16x16x32_bf16(af[i], bf[j], acc[i][j], 0, 0, 0);
  }
#pragma unroll
  for (int i = 0; i < 2; ++i)
#pragma unroll
    for (int j = 0; j < 2; ++j)
#pragma unroll
      for (int rg = 0; rg < 4; ++rg) {
        int rr = rBase + wr * 32 + i * 16 + ((lane >> 4) << 2) + rg;
        int cc = n0 + wc * 32 + j * 16 + (lane & 15);
        C[(size_t)rr * 1536 + cc] = f2b(acc[i][j][rg] + bias[dir * 1536 + cc]);
      }
}

// ---------------------------------------------------------------------------
// GRU step with inline x-projection phases (conductor c1, decoder).
// Tile 32x64, BK=32, reg-prefetch. Round-5 validated.
// ---------------------------------------------------------------------------
struct GruP {
  const float* h_prev; int hs; int hz;
  const ushort_t* Whh;
  const float* x0f; const ushort_t* x0b; int x0s;
  const ushort_t* W0; int w0ld; int K0;
  const float* x1f; int x1sp; const ushort_t* W1; int w1ld; int K1;
  const float* gxf;
  const ushort_t* gxb; int gxros;
  const float* bih; const float* bhh;
  float* h_out; int os;
  ushort_t* h_out2; int o2s;
};
struct GruP2 { GruP d[2]; };

#define LB3(WP, WLD_, G_, KOFF) \
  (*reinterpret_cast<const uint4*>((WP) + (size_t)((G_) * HDIM + c0 + bn) * (size_t)(WLD_) + (KOFF) + bk))

#define AL_H(KOFF, DST)  DST = packA(*reinterpret_cast<const float4*>(p.h_prev + (size_t)(r0 + arow) * p.hs + (KOFF) + ak));
#define AL_X0F(KOFF, DST) DST = packA(*reinterpret_cast<const float4*>(p.x0f + (size_t)(r0 + arow) * p.x0s + (KOFF) + ak));
#define AL_X0B(KOFF, DST) DST = *reinterpret_cast<const uint2*>(p.x0b + (size_t)(r0 + arow) * p.x0s + (KOFF) + ak);
#define AL_CH(KOFF, DST) { int rr_ = r0 + arow; \
  DST = packA(*reinterpret_cast<const float4*>(p.x1f + (size_t)(rr_ & 255) * 12288 + (rr_ >> 8) * 384 + p.x1sp * 96 + (KOFF) + ak)); }

#define GRU_PHASE(KLEN, ALOAD, WP, WLD_, ACCN)                                 \
  { uint2 aC; uint4 b0c, b1c, b2c;                                             \
    ALOAD(0, aC)                                                               \
    b0c = LB3(WP, WLD_, 0, 0); b1c = LB3(WP, WLD_, 1, 0); b2c = LB3(WP, WLD_, 2, 0); \
    for (int k0 = 0; k0 < (KLEN); k0 += 32) {                                  \
      __syncthreads();                                                         \
      *reinterpret_cast<uint2*>(&Xs[arow][ak]) = aC;                           \
      *reinterpret_cast<uint4*>(&Bs[0][bn][bk]) = b0c;                         \
      *reinterpret_cast<uint4*>(&Bs[1][bn][bk]) = b1c;                         \
      *reinterpret_cast<uint4*>(&Bs[2][bn][bk]) = b2c;                         \
      if (k0 + 32 < (KLEN)) {                                                  \
        ALOAD(k0 + 32, aC)                                                     \
        b0c = LB3(WP, WLD_, 0, k0 + 32); b1c = LB3(WP, WLD_, 1, k0 + 32); b2c = LB3(WP, WLD_, 2, k0 + 32); \
      }                                                                        \
      __syncthreads();                                                         \
      bf16x8 afr = *reinterpret_cast<const bf16x8*>(&Xs[wr * 16 + (lane & 15)][(lane >> 4) * 8]); \
      _Pragma("unroll")                                                        \
      for (int j = 0; j < 2; ++j) {                                            \
        const int bc = wc * 32 + j * 16 + (lane & 15);                         \
        bf16x8 f0 = *reinterpret_cast<const bf16x8*>(&Bs[0][bc][(lane >> 4) * 8]); \
        bf16x8 f1 = *reinterpret_cast<const bf16x8*>(&Bs[1][bc][(lane >> 4) * 8]); \
        bf16x8 f2 = *reinterpret_cast<const bf16x8*>(&Bs[2][bc][(lane >> 4) * 8]); \
        aR[j] = __builtin_amdgcn_mfma_f32_16x16x32_bf16(afr, f0, aR[j], 0, 0, 0); \
        aZ[j] = __builtin_amdgcn_mfma_f32_16x16x32_bf16(afr, f1, aZ[j], 0, 0, 0); \
        ACCN[j] = __builtin_amdgcn_mfma_f32_16x16x32_bf16(afr, f2, ACCN[j], 0, 0, 0); \
      }                                                                        \
    } }

__global__ __launch_bounds__(256) void gru_k(GruP2 pp)
{
  const GruP p = pp.d[blockIdx.z];
  __shared__ ushort_t Xs[32][40];
  __shared__ ushort_t Bs[3][64][40];
  const int tid = threadIdx.x;
  const int lane = tid & 63, wv = tid >> 6;
  const int wr = wv >> 1, wc = wv & 1;
  const int r0 = blockIdx.x * 32, c0 = blockIdx.y * 64;
  const int arow = tid >> 3, ak = (tid & 7) * 4;
  const int bn = tid >> 2, bk = (tid & 3) * 8;
  f32x4 aR[2] = {}, aZ[2] = {}, aNX[2] = {}, aNH[2] = {};

  if (!p.hz) { GRU_PHASE(HDIM, AL_H, p.Whh, HDIM, aNH) }
  if (p.K0 > 0) {
    if (p.x0b) { GRU_PHASE(p.K0, AL_X0B, p.W0, p.w0ld, aNX) }
    else       { GRU_PHASE(p.K0, AL_X0F, p.W0, p.w0ld, aNX) }
  }
  if (p.K1 > 0) { GRU_PHASE(p.K1, AL_CH, p.W1, p.w1ld, aNX) }

#pragma unroll
  for (int j = 0; j < 2; ++j) {
#pragma unroll
    for (int rg = 0; rg < 4; ++rg) {
      int r = r0 + wr * 16 + ((lane >> 4) << 2) + rg;
      int c = c0 + wc * 32 + j * 16 + (lane & 15);
      float sr = aR[j][rg] + p.bhh[c];
      float sz = aZ[j][rg] + p.bhh[HDIM + c];
      float nx = aNX[j][rg];
      float nh = aNH[j][rg] + p.bhh[2 * HDIM + c];
      if (p.bih) { sr += p.bih[c]; sz += p.bih[HDIM + c]; nx += p.bih[2 * HDIM + c]; }
      if (p.gxf) {
        const float* g = p.gxf + (size_t)r * GG;
        sr += g[c]; sz += g[HDIM + c]; nx += g[2 * HDIM + c];
      }
      if (p.gxb) {
        const ushort_t* g = p.gxb + (size_t)(p.gxros + r) * 1536;
        sr += b2f(g[c]); sz += b2f(g[HDIM + c]); nx += b2f(g[2 * HDIM + c]);
      }
      float rgate = 1.f / (1.f + expf(-sr));
      float zgate = 1.f / (1.f + expf(-sz));
      float ngate = tanhf(nx + rgate * nh);
      float hp = p.hz ? 0.f : p.h_prev[(size_t)r * p.hs + c];
      float hv = (1.f - zgate) * ngate + zgate * hp;
      p.h_out[(size_t)r * p.os + c] = hv;
      if (p.h_out2) p.h_out2[(size_t)r * p.o2s + c] = f2b(hv);
    }
  }
}

// ---------------------------------------------------------------------------
// Generic MFMA GEMM (f32 A, f32 W cvt on the fly), 32x64 tile.
// ---------------------------------------------------------------------------
__global__ __launch_bounds__(256) void mfma_gemm_k(
    const float* __restrict__ A, int lda,
    const float* __restrict__ W, int ldw,
    const float* __restrict__ bias,
    float* __restrict__ C, int ldc, int N, int K)
{
  __shared__ ushort_t As[32][40];
  __shared__ ushort_t Bs[64][40];
  const int tid = threadIdx.x;
  const int lane = tid & 63, wv = tid >> 6;
  const int wr = wv >> 1, wc = wv & 1;
  const int r0 = blockIdx.x * 32, c0 = blockIdx.y * 64;
  const int arow = tid >> 3, ak = (tid & 7) * 4;
  const int bn = tid >> 2, bk = (tid & 3) * 8;
  f32x4 acc[2] = {};
  const int nOk = (c0 + bn) < N;
  const float* wrow = W + (size_t)(nOk ? (c0 + bn) : 0) * ldw;

  uint2 aC = packA(*reinterpret_cast<const float4*>(A + (size_t)(r0 + arow) * lda + ak));
  uint4 bC;
  {
    float4 v0 = *reinterpret_cast<const float4*>(wrow + bk);
    float4 v1 = *reinterpret_cast<const float4*>(wrow + bk + 4);
    bC = packA8(v0, v1);
  }
  for (int k0 = 0; k0 < K; k0 += 32) {
    __syncthreads();
    *reinterpret_cast<uint2*>(&As[arow][ak]) = aC;
    if (nOk) *reinterpret_cast<uint4*>(&Bs[bn][bk]) = bC;
    else { uint4 z; z.x = z.y = z.z = z.w = 0; *reinterpret_cast<uint4*>(&Bs[bn][bk]) = z; }
    if (k0 + 32 < K) {
      aC = packA(*reinterpret_cast<const float4*>(A + (size_t)(r0 + arow) * lda + k0 + 32 + ak));
      float4 v0 = *reinterpret_cast<const float4*>(wrow + k0 + 32 + bk);
      float4 v1 = *reinterpret_cast<const float4*>(wrow + k0 + 32 + bk + 4);
      bC = packA8(v0, v1);
    }
    __syncthreads();
    bf16x8 afr = *reinterpret_cast<const bf16x8*>(&As[wr * 16 + (lane & 15)][(lane >> 4) * 8]);
#pragma unroll
    for (int j = 0; j < 2; ++j) {
      bf16x8 bfr = *reinterpret_cast<const bf16x8*>(&Bs[wc * 32 + j * 16 + (lane & 15)][(lane >> 4) * 8]);
      acc[j] = __builtin_amdgcn_mfma_f32_16x16x32_bf16(afr, bfr, acc[j], 0, 0, 0);
    }
  }
#pragma unroll
  for (int j = 0; j < 2; ++j)
#pragma unroll
    for (int rg = 0; rg < 4; ++rg) {
      int r = r0 + wr * 16 + ((lane >> 4) << 2) + rg;
      int c = c0 + wc * 32 + j * 16 + (lane & 15);
      if (c < N) C[(size_t)r * ldc + c] = acc[j][rg] + (bias ? bias[c] : 0.f);
    }
}

// ---------------------------------------------------------------------------
// Small elementwise kernels
// ---------------------------------------------------------------------------
__global__ void gather_hidden_k(const ushort_t* __restrict__ y0b,
                                const float* __restrict__ h1f,
                                const float* __restrict__ h1b,
                                float* __restrict__ hidden)
{
  int i = blockIdx.x * 256 + threadIdx.x;
  if (i >= BB * 4 * HDIM) return;
  int b = i >> 11, j = i & 2047;
  float v;
  if (j < 512)       v = b2f(y0b[(size_t)b * 131072 + 127 * 1024 + j]);
  else if (j < 1024) v = b2f(y0b[(size_t)b * 131072 + j]);
  else if (j < 1536) v = h1f[b * 512 + (j - 1024)];
  else               v = h1b[b * 512 + (j - 1536)];
  hidden[i] = v;
}

__global__ void z_k(const float* __restrict__ mu, const float* __restrict__ lv,
                    const float* __restrict__ eps, float* __restrict__ z,
                    float* __restrict__ out_mu, float* __restrict__ out_lv)
{
  int i = blockIdx.x * 256 + threadIdx.x;
  if (i >= BB * HDIM) return;
  float m = mu[i], l = lv[i];
  z[i] = eps[i] * expf(0.5f * l) + m;
  out_mu[i] = m;
  out_lv[i] = l;
}

__global__ void softmax_k(const float* __restrict__ logits,
                          float* __restrict__ out_sm,
                          float* __restrict__ out_lsm)
{
  int q = blockIdx.x;
  int lane = threadIdx.x;
  const float* row = logits + (size_t)q * 96;
  float v0 = row[lane];
  float v1 = (lane < 32) ? row[lane + 64] : -1e30f;
  float m = fmaxf(v0, v1);
#pragma unroll
  for (int o = 32; o; o >>= 1) m = fmaxf(m, __shfl_xor(m, o));
  float e0 = expf(v0 - m);
  float e1 = (lane < 32) ? expf(v1 - m) : 0.f;
  float s = e0 + e1;
#pragma unroll
  for (int o = 32; o; o >>= 1) s += __shfl_xor(s, o);
  float inv = 1.f / s, ls = logf(s);
  int b = (q >> 2) & 255;
  int t = (q >> 10) * 4 + (q & 3);
  size_t base = (size_t)b * TT * 96 + (size_t)t * 96;
  out_sm[base + lane]  = e0 * inv;
  out_lsm[base + lane] = v0 - m - ls;
  if (lane < 32) {
    out_sm[base + lane + 64]  = e1 * inv;
    out_lsm[base + lane + 64] = v1 - m - ls;
  }
}

__global__ void echo_k(const float* __restrict__ in, float* __restrict__ out)
{
  int i = blockIdx.x * 256 + threadIdx.x;
  if (i < BB * TT * NCC) out[i] = in[i];
}

// ---------------------------------------------------------------------------
extern "C" void kernel_launch(void* const* d_in, const int* in_sizes, int n_in,
                              void* d_out, int out_size, void* d_ws, size_t ws_size,
                              hipStream_t stream)
{
  const float* in        = (const float*)d_in[0];
  const float* eps       = (const float*)d_in[2];
  const float* enc0_Wih  = (const float*)d_in[3];
  const float* enc0_Whh  = (const float*)d_in[4];
  const float* enc0_bih  = (const float*)d_in[5];
  const float* enc0_bhh  = (const float*)d_in[6];
  const float* enc1_Wih  = (const float*)d_in[7];
  const float* enc1_Whh  = (const float*)d_in[8];
  const float* enc1_bih  = (const float*)d_in[9];
  const float* enc1_bhh  = (const float*)d_in[10];
  const float* con0_Wih  = (const float*)d_in[11];
  const float* con0_Whh  = (const float*)d_in[12];
  const float* con0_bih  = (const float*)d_in[13];
  const float* con0_bhh  = (const float*)d_in[14];
  const float* con1_Wih  = (const float*)d_in[15];
  const float* con1_Whh  = (const float*)d_in[16];
  const float* con1_bih  = (const float*)d_in[17];
  const float* con1_bhh  = (const float*)d_in[18];
  const float* dec0_Wih  = (const float*)d_in[19];
  const float* dec0_Whh  = (const float*)d_in[20];
  const float* dec0_bih  = (const float*)d_in[21];
  const float* dec0_bhh  = (const float*)d_in[22];
  const float* dec1_Wih  = (const float*)d_in[23];
  const float* dec1_Whh  = (const float*)d_in[24];
  const float* dec1_bih  = (const float*)d_in[25];
  const float* dec1_bhh  = (const float*)d_in[26];
  const float* W_mu      = (const float*)d_in[27];
  const float* b_mu      = (const float*)d_in[28];
  const float* W_lv      = (const float*)d_in[29];
  const float* b_lv      = (const float*)d_in[30];
  const float* W_ci      = (const float*)d_in[31];
  const float* b_ci      = (const float*)d_in[32];
  const float* W_ch      = (const float*)d_in[33];
  const float* b_ch      = (const float*)d_in[34];
  const float* W_out     = (const float*)d_in[35];
  const float* b_out     = (const float*)d_in[36];

  // ---- workspace layout (f32 slots; 33,554,432 = 128 MiB exactly) ----------
  float* ws = (float*)d_ws;
  ushort_t* y0b  = (ushort_t*)ws;                      // [256][128][1024] bf16 @0..16,777,216
  float* e0pp    = ws + 16777216;                      // [2pp][2dir][256][512] ..17,301,504
  ushort_t* gxAll = (ushort_t*)(ws + 17301504);        // [2][4096][1536] bf16 ..23,592,960
  // decoder-phase aliases (y0b/e0pp/gxAll dead):
  float* h0c   = ws;                                   // [32][256][512]
  float* h1c   = ws + 4194304;
  float* d0p[2] = { ws + 8388608,  ws + 12582912 };
  float* d1p[2] = { ws + 16777216, ws + 20971520 };    // ends 25,165,824
  // persistent smalls @26,492,928
  float* mu_f  = ws + 26492928;
  float* lv_f  = ws + 26624000;
  float* zz    = ws + 26755072;
  float* ci    = ws + 26886144;
  float* chv   = ws + 26910720;
  float* gx_c0 = ws + 27041792;                        // ends 27,435,008
  ushort_t* Wb = (ushort_t*)(ws + 27435008);           // 12,238,848 bf16 -> 33,554,432

  ushort_t* wb_e0_Wih = Wb;
  ushort_t* wb_e0_Whh = Wb + 294912;
  ushort_t* wb_e1_Wih = Wb + 1867776;
  ushort_t* wb_e1_Whh = Wb + 5013504;
  ushort_t* wb_c0_Whh = Wb + 6586368;
  ushort_t* wb_c1_Wih = Wb + 7372800;
  ushort_t* wb_c1_Whh = Wb + 8159232;
  ushort_t* wb_d0_Wih = Wb + 8945664;
  ushort_t* wb_d0_Whh = Wb + 9879552;
  ushort_t* wb_d1_Wih = Wb + 10665984;
  ushort_t* wb_d1_Whh = Wb + 11452416;

  float* outp   = (float*)d_out;
  float* out_sm = outp;
  float* out_ls = outp + 3145728;
  float* out_mu = outp + 6291456;
  float* out_lv = outp + 6422528;
  float* out_ec = outp + 6553600;
  // scratch in echo region (dead before echo_k)
  float* fscr = out_ec;
  float* h1f_pp[2] = { fscr,          fscr + 131072 };
  float* h1b_pp[2] = { fscr + 262144, fscr + 393216 };
  float* hidden    = fscr + 524288;                    // [256][2048]
  float* logits_q  = out_ec;                           // decoder: [8192 x 384]

  auto cvt = [&](const float* s, ushort_t* d, int n) {
    cvt_bf16_k<<<(n / 4 + 255) / 256, 256, 0, stream>>>(s, d, n / 4);
  };
  auto gemmM = [&](const float* A, int lda, const float* W, int ldw, const float* bias,
                   float* C, int ldc, int M, int N, int K) {
    mfma_gemm_k<<<dim3(M / 32, (N + 63) / 64), 256, 0, stream>>>(A, lda, W, ldw, bias, C, ldc, N, K);
  };
  auto gru1 = [&](const GruP& a, int rows) {
    GruP2 q; q.d[0] = a; q.d[1] = a;
    gru_k<<<dim3(rows / 32, 8, 1), 256, 0, stream>>>(q);
  };

  // ---------------- weight conversion ---------------------------------------
  cvt(enc0_Wih, wb_e0_Wih, 294912);
  cvt(enc0_Whh, wb_e0_Whh, 1572864);
  cvt(enc1_Wih, wb_e1_Wih, 3145728);
  cvt(enc1_Whh, wb_e1_Whh, 1572864);
  cvt(con0_Whh, wb_c0_Whh, 786432);
  cvt(con1_Wih, wb_c1_Wih, 786432);
  cvt(con1_Whh, wb_c1_Whh, 786432);
  cvt(dec0_Wih, wb_d0_Wih, 933888);
  cvt(dec0_Whh, wb_d0_Whh, 786432);
  cvt(dec1_Wih, wb_d1_Wih, 786432);
  cvt(dec1_Whh, wb_d1_Whh, 786432);

  // ---------------- encoder layer 0 (gx hoisted, 8 chunks x 16 steps) --------
  for (int ch = 0; ch < 8; ++ch) {
    int t0 = ch * 16;
    gx_gemm_k<1><<<dim3(128, 12), 512, 0, stream>>>(
        (const void*)in, wb_e0_Wih, 96, 147456, enc0_bih, gxAll, t0, 96);
    for (int tl = 0; tl < 16; ++tl) {
      int t = t0 + tl;
      StepP f = {};
      f.hz = (t == 0);
      f.h_prev = e0pp + (size_t)((t + 1) & 1) * 262144;
      f.whh = wb_e0_Whh; f.bhh = enc0_bhh;
      f.gxb = gxAll; f.gxros = tl * 256;
      f.h_out = e0pp + (size_t)(t & 1) * 262144;
      f.y0o = y0b + (size_t)t * 1024; f.y0st = 131072;
      StepP bd = {};
      bd.hz = (t == 0);
      bd.h_prev = e0pp + (size_t)((t + 1) & 1) * 262144 + 131072;
      bd.whh = wb_e0_Whh + 786432; bd.bhh = enc0_bhh + GG;
      bd.gxb = gxAll + 6291456; bd.gxros = tl * 256;
      bd.h_out = e0pp + (size_t)(t & 1) * 262144 + 131072;
      bd.y0o = y0b + (size_t)(127 - t) * 1024 + 512; bd.y0st = 131072;
      StepP2 q; q.d[0] = f; q.d[1] = bd;
      step_k<<<dim3(8, 8, 2), 256, 0, stream>>>(q);
    }
  }

  // ---------------- encoder layer 1 (gx hoisted, 8 chunks) -------------------
  for (int ch = 0; ch < 8; ++ch) {
    int t0 = ch * 16;
    gx_gemm_k<0><<<dim3(128, 12), 512, 0, stream>>>(
        (const void*)y0b, wb_e1_Wih, 1024, 1572864, enc1_bih, gxAll, t0, 1024);
    for (int tl = 0; tl < 16; ++tl) {
      int t = t0 + tl;
      StepP f = {};
      f.hz = (t == 0);
      f.h_prev = h1f_pp[(t + 1) & 1];
      f.whh = wb_e1_Whh; f.bhh = enc1_bhh;
      f.gxb = gxAll; f.gxros = tl * 256;
      f.h_out = h1f_pp[t & 1];
      StepP bd = {};
      bd.hz = (t == 0);
      bd.h_prev = h1b_pp[(t + 1) & 1];
      bd.whh = wb_e1_Whh + 786432; bd.bhh = enc1_bhh + GG;
      bd.gxb = gxAll + 6291456; bd.gxros = tl * 256;
      bd.h_out = h1b_pp[t & 1];
      StepP2 q; q.d[0] = f; q.d[1] = bd;
      step_k<<<dim3(8, 8, 2), 256, 0, stream>>>(q);
    }
  }

  // ---------------- latent ----------------------------------------------------
  gather_hidden_k<<<2048, 256, 0, stream>>>(y0b, h1f_pp[1], h1b_pp[1], hidden);
  gemmM(hidden, 2048, W_mu, 2048, b_mu, mu_f, 512, BB, 512, 2048);
  gemmM(hidden, 2048, W_lv, 2048, b_lv, lv_f, 512, BB, 512, 2048);
  z_k<<<512, 256, 0, stream>>>(mu_f, lv_f, eps, zz, out_mu, out_lv);
  gemmM(zz, 512, W_ci, 512, b_ci, ci, 96, BB, 96, 512);
  gemmM(zz, 512, W_ch, 512, b_ch, chv, 512, BB, 512, 512);
  gemmM(ci, 96, con0_Wih, 96, con0_bih, gx_c0, GG, BB, GG, 96);

  // ---------------- conductor (64 cells; c0 via step_k, c1 via gru_k) --------
  for (int bar = 0; bar < NBB; ++bar) {
    StepP c0 = {};
    c0.h_prev = (bar == 0) ? chv : h0c + (size_t)(bar - 1) * 131072;
    c0.whh = wb_c0_Whh; c0.bhh = con0_bhh;
    c0.gxf = gx_c0;
    c0.h_out = h0c + (size_t)bar * 131072;
    StepP2 q; q.d[0] = c0; q.d[1] = c0;
    step_k<<<dim3(8, 8, 1), 256, 0, stream>>>(q);
    GruP c1 = {};
    c1.h_prev = (bar == 0) ? chv : h1c + (size_t)(bar - 1) * 131072; c1.hs = 512;
    c1.x0f = h0c + (size_t)bar * 131072; c1.x0s = 512;
    c1.W0 = wb_c1_Wih; c1.w0ld = 512; c1.K0 = 512;
    c1.Whh = wb_c1_Whh; c1.bih = con1_bih; c1.bhh = con1_bhh;
    c1.h_out = h1c + (size_t)bar * 131072; c1.os = 512;
    gru1(c1, BB);
  }

  // ---------------- decoder: 8192 rows, 4 steps -------------------------------
  const int R = NBB * BB;
  for (int s = 0; s < CPBB; ++s) {
    GruP d0 = {};
    d0.h_prev = (s == 0) ? h0c : d0p[(s - 1) & 1]; d0.hs = 512;
    d0.x0f = h1c; d0.x0s = 512; d0.W0 = wb_d0_Wih; d0.w0ld = 608; d0.K0 = 512;
    d0.x1f = in; d0.x1sp = s; d0.W1 = wb_d0_Wih + 512; d0.w1ld = 608; d0.K1 = 96;
    d0.Whh = wb_d0_Whh; d0.bih = dec0_bih; d0.bhh = dec0_bhh;
    d0.h_out = d0p[s & 1]; d0.os = 512;
    gru1(d0, R);
    GruP d1 = {};
    d1.h_prev = (s == 0) ? h1c : d1p[(s - 1) & 1]; d1.hs = 512;
    d1.x0f = d0p[s & 1]; d1.x0s = 512; d1.W0 = wb_d1_Wih; d1.w0ld = 512; d1.K0 = 512;
    d1.Whh = wb_d1_Whh; d1.bih = dec1_bih; d1.bhh = dec1_bhh;
    d1.h_out = d1p[s & 1]; d1.os = 512;
    gru1(d1, R);
    gemmM(d1p[s & 1], 512, W_out, 512, b_out, logits_q + (size_t)s * 96, 384, R, 96, 512);
  }

  // ---------------- softmax + echo --------------------------------------------
  softmax_k<<<NBB * BB * CPBB, 64, 0, stream>>>(logits_q, out_sm, out_ls);
  echo_k<<<12288, 256, 0, stream>>>(in, out_ec);
}

// Round 8
// 8129.909 us; speedup vs baseline: 1.7468x; 1.2787x over previous
//
#include <hip/hip_runtime.h>

// MusicVAE forward. B=256, T=128, NC=96, H=512, G=1536, NB=32, CPB=4.
// All inputs f32; all outputs f32. bf16 MFMA compute, f32 state/accumulate.
// Sequential GRU steps use hstep_k: A-tile staged once in LDS (1 barrier),
// weights streamed global->MFMA B-frags with NO barriers in the K-loop.

#define BB   256
#define TT   128
#define NCC  96
#define HDIM 512
#define GG   1536
#define NBB  32
#define CPBB 4

typedef __attribute__((ext_vector_type(4))) float f32x4;
typedef __attribute__((ext_vector_type(8))) short bf16x8;
typedef unsigned short ushort_t;

__device__ __forceinline__ unsigned short f2b(float x) {
  unsigned int u = __builtin_bit_cast(unsigned int, x);
  u += 0x7fff + ((u >> 16) & 1);
  return (unsigned short)(u >> 16);
}
__device__ __forceinline__ float b2f(unsigned short h) {
  unsigned int u = ((unsigned int)h) << 16;
  return __builtin_bit_cast(float, u);
}
__device__ __forceinline__ uint2 packA(float4 v) {
  uint2 r;
  r.x = (unsigned)f2b(v.x) | ((unsigned)f2b(v.y) << 16);
  r.y = (unsigned)f2b(v.z) | ((unsigned)f2b(v.w) << 16);
  return r;
}
__device__ __forceinline__ uint4 packA8(float4 v0, float4 v1) {
  uint4 r;
  r.x = (unsigned)f2b(v0.x) | ((unsigned)f2b(v0.y) << 16);
  r.y = (unsigned)f2b(v0.z) | ((unsigned)f2b(v0.w) << 16);
  r.z = (unsigned)f2b(v1.x) | ((unsigned)f2b(v1.y) << 16);
  r.w = (unsigned)f2b(v1.z) | ((unsigned)f2b(v1.w) << 16);
  return r;
}

__global__ void cvt_bf16_k(const float* __restrict__ s, ushort_t* __restrict__ d, int n4) {
  int i = blockIdx.x * 256 + threadIdx.x;
  if (i >= n4) return;
  float4 v = reinterpret_cast<const float4*>(s)[i];
  ushort4 o;
  o.x = f2b(v.x); o.y = f2b(v.y); o.z = f2b(v.z); o.w = f2b(v.w);
  reinterpret_cast<ushort4*>(d)[i] = o;
}

// ---------------------------------------------------------------------------
// hstep_k: sequential GRU step, barrier-free weight streaming.
// Tile 32 rows x 64 cols, 256 thr (4 waves: wr row-half x wc col-half).
// A (h_prev, and optional x0) staged bf16 in LDS once; weights loaded
// per-lane as direct MFMA B-fragments (16B each) with no LDS staging.
// ---------------------------------------------------------------------------
struct HP {
  const float* h_prev; int hz;
  const ushort_t* whh;            // [1536][512] bf16
  const float* bhh;               // [1536]
  const float* x0; int x0s;       // optional inline x (f32 rows, stride x0s)
  const ushort_t* w0;             // [1536][96] bf16
  int k0n;                        // 96 or 0
  const float* bih;               // with inline x (else null)
  const ushort_t* gxb; int gxros; // bf16 gx (bih folded), rows gxros+r
  const float* gxf;               // f32 gx rows r, stride 1536 (bih folded)
  float* h_out;
  ushort_t* y0o; int y0st;        // optional bf16 mirror
};
struct HP2 { HP d[2]; };

__global__ __launch_bounds__(256) void hstep_k(HP2 pp)
{
  const HP p = pp.d[blockIdx.z];
  __shared__ ushort_t Ah[32][512];   // kb-blocks XOR-swizzled by (row&7)
  __shared__ ushort_t Ax[32][104];   // padded, no swizzle
  const int tid = threadIdx.x;
  const int lane = tid & 63, wv = tid >> 6;
  const int wr = wv >> 1, wc = wv & 1;
  const int r0 = blockIdx.x * 32, c0 = blockIdx.y * 64;
  f32x4 aR[2] = {}, aZ[2] = {}, aNH[2] = {}, aNX[2] = {};

  if (!p.hz) {
#pragma unroll
    for (int i = 0; i < 8; ++i) {
      int flat = tid + i * 256;          // 0..2047
      int row = flat >> 6, kb = flat & 63;
      const float4* src = reinterpret_cast<const float4*>(
          p.h_prev + (size_t)(r0 + row) * 512 + kb * 8);
      *reinterpret_cast<uint4*>(&Ah[row][(kb ^ (row & 7)) << 3]) = packA8(src[0], src[1]);
    }
  }
  if (p.k0n) {
#pragma unroll
    for (int i = 0; i < 2; ++i) {
      int flat = tid + i * 256;
      if (flat < 384) {                  // 32 rows x 12 kb
        int row = flat / 12, kb = flat - row * 12;
        const float4* src = reinterpret_cast<const float4*>(
            p.x0 + (size_t)(r0 + row) * p.x0s + kb * 8);
        *reinterpret_cast<uint4*>(&Ax[row][kb << 3]) = packA8(src[0], src[1]);
      }
    }
  }
  __syncthreads();

  const int arow = wr * 16 + (lane & 15);
  const int kbl = lane >> 4;             // 0..3
  const int col0 = c0 + wc * 32 + (lane & 15);

  if (!p.hz) {
    const ushort_t* wbase = p.whh + (size_t)col0 * 512 + kbl * 8;
#pragma unroll 4
    for (int kc = 0; kc < 16; ++kc) {
      bf16x8 af = *reinterpret_cast<const bf16x8*>(
          &Ah[arow][(((kc << 2) + kbl) ^ (arow & 7)) << 3]);
#pragma unroll
      for (int j = 0; j < 2; ++j) {
        const ushort_t* wp = wbase + (size_t)(j * 16) * 512 + (kc << 5);
        bf16x8 b0 = *reinterpret_cast<const bf16x8*>(wp);
        bf16x8 b1 = *reinterpret_cast<const bf16x8*>(wp + 262144);
        bf16x8 b2 = *reinterpret_cast<const bf16x8*>(wp + 524288);
        aR[j]  = __builtin_amdgcn_mfma_f32_16x16x32_bf16(af, b0, aR[j], 0, 0, 0);
        aZ[j]  = __builtin_amdgcn_mfma_f32_16x16x32_bf16(af, b1, aZ[j], 0, 0, 0);
        aNH[j] = __builtin_amdgcn_mfma_f32_16x16x32_bf16(af, b2, aNH[j], 0, 0, 0);
      }
    }
  }
  if (p.k0n) {
    const ushort_t* wbase = p.w0 + (size_t)col0 * 96 + kbl * 8;
#pragma unroll
    for (int kc = 0; kc < 3; ++kc) {
      bf16x8 af = *reinterpret_cast<const bf16x8*>(&Ax[arow][((kc << 2) + kbl) << 3]);
#pragma unroll
      for (int j = 0; j < 2; ++j) {
        const ushort_t* wp = wbase + (size_t)(j * 16) * 96 + (kc << 5);
        bf16x8 b0 = *reinterpret_cast<const bf16x8*>(wp);
        bf16x8 b1 = *reinterpret_cast<const bf16x8*>(wp + 49152);
        bf16x8 b2 = *reinterpret_cast<const bf16x8*>(wp + 98304);
        aR[j]  = __builtin_amdgcn_mfma_f32_16x16x32_bf16(af, b0, aR[j], 0, 0, 0);
        aZ[j]  = __builtin_amdgcn_mfma_f32_16x16x32_bf16(af, b1, aZ[j], 0, 0, 0);
        aNX[j] = __builtin_amdgcn_mfma_f32_16x16x32_bf16(af, b2, aNX[j], 0, 0, 0);
      }
    }
  }

#pragma unroll
  for (int j = 0; j < 2; ++j) {
#pragma unroll
    for (int rg = 0; rg < 4; ++rg) {
      int r = r0 + wr * 16 + ((lane >> 4) << 2) + rg;
      int c = c0 + wc * 32 + j * 16 + (lane & 15);
      float sr = aR[j][rg] + p.bhh[c];
      float sz = aZ[j][rg] + p.bhh[512 + c];
      float nh = aNH[j][rg] + p.bhh[1024 + c];
      float nx = aNX[j][rg];
      if (p.bih) { sr += p.bih[c]; sz += p.bih[512 + c]; nx += p.bih[1024 + c]; }
      if (p.gxb) {
        const ushort_t* g = p.gxb + (size_t)(p.gxros + r) * 1536;
        sr += b2f(g[c]); sz += b2f(g[512 + c]); nx += b2f(g[1024 + c]);
      }
      if (p.gxf) {
        const float* g = p.gxf + (size_t)r * 1536;
        sr += g[c]; sz += g[512 + c]; nx += g[1024 + c];
      }
      float rgate = 1.f / (1.f + expf(-sr));
      float zgate = 1.f / (1.f + expf(-sz));
      float ngate = tanhf(nx + rgate * nh);
      float hp = p.hz ? 0.f : p.h_prev[(size_t)r * 512 + c];
      float hv = (1.f - zgate) * ngate + zgate * hp;
      p.h_out[(size_t)r * 512 + c] = hv;
      if (p.y0o) p.y0o[(size_t)r * p.y0st + c] = f2b(hv);
    }
  }
}

// ---------------------------------------------------------------------------
// Chunk GEMM (round-5 proven): gx = y0b(b,t) @ W^T + bias -> bf16.
// M=4096 (16 t x 256 b), N=1536, K=1024. Tile 32x64, 256 thr, reg-prefetch.
// ---------------------------------------------------------------------------
__global__ __launch_bounds__(256) void gemm_chunk_k(
    const ushort_t* __restrict__ A, int tstep,
    const ushort_t* __restrict__ W,
    const float* __restrict__ bias,
    ushort_t* __restrict__ C)
{
  __shared__ ushort_t As[32][40];
  __shared__ ushort_t Bs[64][40];
  const int tid = threadIdx.x;
  const int lane = tid & 63, wv = tid >> 6;
  const int wr = wv >> 1, wc = wv & 1;
  const int r0 = blockIdx.x * 32, c0 = blockIdx.y * 64;
  const int arow = tid >> 3, ak = (tid & 7) * 4;
  const int bn = tid >> 2, bk = (tid & 3) * 8;
  f32x4 acc[2] = {};
  const int rr = r0 + arow;
  const ushort_t* arowp = A + (long)(rr & 255) * 131072 + (long)(rr >> 8) * tstep;
  const ushort_t* wrow = W + (size_t)(c0 + bn) * 1024;

  uint2 aC = *reinterpret_cast<const uint2*>(arowp + ak);
  uint4 bC = *reinterpret_cast<const uint4*>(wrow + bk);
  for (int k0 = 0; k0 < 1024; k0 += 32) {
    __syncthreads();
    *reinterpret_cast<uint2*>(&As[arow][ak]) = aC;
    *reinterpret_cast<uint4*>(&Bs[bn][bk]) = bC;
    if (k0 + 32 < 1024) {
      aC = *reinterpret_cast<const uint2*>(arowp + k0 + 32 + ak);
      bC = *reinterpret_cast<const uint4*>(wrow + k0 + 32 + bk);
    }
    __syncthreads();
    bf16x8 afr = *reinterpret_cast<const bf16x8*>(&As[wr * 16 + (lane & 15)][(lane >> 4) * 8]);
#pragma unroll
    for (int j = 0; j < 2; ++j) {
      bf16x8 bfr = *reinterpret_cast<const bf16x8*>(&Bs[wc * 32 + j * 16 + (lane & 15)][(lane >> 4) * 8]);
      acc[j] = __builtin_amdgcn_mfma_f32_16x16x32_bf16(afr, bfr, acc[j], 0, 0, 0);
    }
  }
#pragma unroll
  for (int j = 0; j < 2; ++j)
#pragma unroll
    for (int rg = 0; rg < 4; ++rg) {
      int r = r0 + wr * 16 + ((lane >> 4) << 2) + rg;
      int c = c0 + wc * 32 + j * 16 + (lane & 15);
      C[(size_t)r * 1536 + c] = f2b(acc[j][rg] + bias[c]);
    }
}

// ---------------------------------------------------------------------------
// GRU step with inline x-projection phases (conductor c1, decoder).
// Tile 32x64, BK=32, reg-prefetch. Round-5 validated.
// ---------------------------------------------------------------------------
struct GruP {
  const float* h_prev; int hs; int hz;
  const ushort_t* Whh;
  const float* x0f; const ushort_t* x0b; int x0s;
  const ushort_t* W0; int w0ld; int K0;
  const float* x1f; int x1sp; const ushort_t* W1; int w1ld; int K1;
  const float* gxf;
  const ushort_t* gxb; int gxros;
  const float* bih; const float* bhh;
  float* h_out; int os;
  ushort_t* h_out2; int o2s;
};
struct GruP2 { GruP d[2]; };

#define LB3(WP, WLD_, G_, KOFF) \
  (*reinterpret_cast<const uint4*>((WP) + (size_t)((G_) * HDIM + c0 + bn) * (size_t)(WLD_) + (KOFF) + bk))

#define AL_H(KOFF, DST)  DST = packA(*reinterpret_cast<const float4*>(p.h_prev + (size_t)(r0 + arow) * p.hs + (KOFF) + ak));
#define AL_X0F(KOFF, DST) DST = packA(*reinterpret_cast<const float4*>(p.x0f + (size_t)(r0 + arow) * p.x0s + (KOFF) + ak));
#define AL_X0B(KOFF, DST) DST = *reinterpret_cast<const uint2*>(p.x0b + (size_t)(r0 + arow) * p.x0s + (KOFF) + ak);
#define AL_CH(KOFF, DST) { int rr_ = r0 + arow; \
  DST = packA(*reinterpret_cast<const float4*>(p.x1f + (size_t)(rr_ & 255) * 12288 + (rr_ >> 8) * 384 + p.x1sp * 96 + (KOFF) + ak)); }

#define GRU_PHASE(KLEN, ALOAD, WP, WLD_, ACCN)                                 \
  { uint2 aC; uint4 b0c, b1c, b2c;                                             \
    ALOAD(0, aC)                                                               \
    b0c = LB3(WP, WLD_, 0, 0); b1c = LB3(WP, WLD_, 1, 0); b2c = LB3(WP, WLD_, 2, 0); \
    for (int k0 = 0; k0 < (KLEN); k0 += 32) {                                  \
      __syncthreads();                                                         \
      *reinterpret_cast<uint2*>(&Xs[arow][ak]) = aC;                           \
      *reinterpret_cast<uint4*>(&Bs[0][bn][bk]) = b0c;                         \
      *reinterpret_cast<uint4*>(&Bs[1][bn][bk]) = b1c;                         \
      *reinterpret_cast<uint4*>(&Bs[2][bn][bk]) = b2c;                         \
      if (k0 + 32 < (KLEN)) {                                                  \
        ALOAD(k0 + 32, aC)                                                     \
        b0c = LB3(WP, WLD_, 0, k0 + 32); b1c = LB3(WP, WLD_, 1, k0 + 32); b2c = LB3(WP, WLD_, 2, k0 + 32); \
      }                                                                        \
      __syncthreads();                                                         \
      bf16x8 afr = *reinterpret_cast<const bf16x8*>(&Xs[wr * 16 + (lane & 15)][(lane >> 4) * 8]); \
      _Pragma("unroll")                                                        \
      for (int j = 0; j < 2; ++j) {                                            \
        const int bc = wc * 32 + j * 16 + (lane & 15);                         \
        bf16x8 f0 = *reinterpret_cast<const bf16x8*>(&Bs[0][bc][(lane >> 4) * 8]); \
        bf16x8 f1 = *reinterpret_cast<const bf16x8*>(&Bs[1][bc][(lane >> 4) * 8]); \
        bf16x8 f2 = *reinterpret_cast<const bf16x8*>(&Bs[2][bc][(lane >> 4) * 8]); \
        aR[j] = __builtin_amdgcn_mfma_f32_16x16x32_bf16(afr, f0, aR[j], 0, 0, 0); \
        aZ[j] = __builtin_amdgcn_mfma_f32_16x16x32_bf16(afr, f1, aZ[j], 0, 0, 0); \
        ACCN[j] = __builtin_amdgcn_mfma_f32_16x16x32_bf16(afr, f2, ACCN[j], 0, 0, 0); \
      }                                                                        \
    } }

__global__ __launch_bounds__(256) void gru_k(GruP2 pp)
{
  const GruP p = pp.d[blockIdx.z];
  __shared__ ushort_t Xs[32][40];
  __shared__ ushort_t Bs[3][64][40];
  const int tid = threadIdx.x;
  const int lane = tid & 63, wv = tid >> 6;
  const int wr = wv >> 1, wc = wv & 1;
  const int r0 = blockIdx.x * 32, c0 = blockIdx.y * 64;
  const int arow = tid >> 3, ak = (tid & 7) * 4;
  const int bn = tid >> 2, bk = (tid & 3) * 8;
  f32x4 aR[2] = {}, aZ[2] = {}, aNX[2] = {}, aNH[2] = {};

  if (!p.hz) { GRU_PHASE(HDIM, AL_H, p.Whh, HDIM, aNH) }
  if (p.K0 > 0) {
    if (p.x0b) { GRU_PHASE(p.K0, AL_X0B, p.W0, p.w0ld, aNX) }
    else       { GRU_PHASE(p.K0, AL_X0F, p.W0, p.w0ld, aNX) }
  }
  if (p.K1 > 0) { GRU_PHASE(p.K1, AL_CH, p.W1, p.w1ld, aNX) }

#pragma unroll
  for (int j = 0; j < 2; ++j) {
#pragma unroll
    for (int rg = 0; rg < 4; ++rg) {
      int r = r0 + wr * 16 + ((lane >> 4) << 2) + rg;
      int c = c0 + wc * 32 + j * 16 + (lane & 15);
      float sr = aR[j][rg] + p.bhh[c];
      float sz = aZ[j][rg] + p.bhh[HDIM + c];
      float nx = aNX[j][rg];
      float nh = aNH[j][rg] + p.bhh[2 * HDIM + c];
      if (p.bih) { sr += p.bih[c]; sz += p.bih[HDIM + c]; nx += p.bih[2 * HDIM + c]; }
      if (p.gxf) {
        const float* g = p.gxf + (size_t)r * GG;
        sr += g[c]; sz += g[HDIM + c]; nx += g[2 * HDIM + c];
      }
      if (p.gxb) {
        const ushort_t* g = p.gxb + (size_t)(p.gxros + r) * 1536;
        sr += b2f(g[c]); sz += b2f(g[HDIM + c]); nx += b2f(g[2 * HDIM + c]);
      }
      float rgate = 1.f / (1.f + expf(-sr));
      float zgate = 1.f / (1.f + expf(-sz));
      float ngate = tanhf(nx + rgate * nh);
      float hp = p.hz ? 0.f : p.h_prev[(size_t)r * p.hs + c];
      float hv = (1.f - zgate) * ngate + zgate * hp;
      p.h_out[(size_t)r * p.os + c] = hv;
      if (p.h_out2) p.h_out2[(size_t)r * p.o2s + c] = f2b(hv);
    }
  }
}

// ---------------------------------------------------------------------------
// Generic MFMA GEMM (f32 A, f32 W cvt on the fly), 32x64 tile.
// ---------------------------------------------------------------------------
__global__ __launch_bounds__(256) void mfma_gemm_k(
    const float* __restrict__ A, int lda,
    const float* __restrict__ W, int ldw,
    const float* __restrict__ bias,
    float* __restrict__ C, int ldc, int N, int K)
{
  __shared__ ushort_t As[32][40];
  __shared__ ushort_t Bs[64][40];
  const int tid = threadIdx.x;
  const int lane = tid & 63, wv = tid >> 6;
  const int wr = wv >> 1, wc = wv & 1;
  const int r0 = blockIdx.x * 32, c0 = blockIdx.y * 64;
  const int arow = tid >> 3, ak = (tid & 7) * 4;
  const int bn = tid >> 2, bk = (tid & 3) * 8;
  f32x4 acc[2] = {};
  const int nOk = (c0 + bn) < N;
  const float* wrow = W + (size_t)(nOk ? (c0 + bn) : 0) * ldw;

  uint2 aC = packA(*reinterpret_cast<const float4*>(A + (size_t)(r0 + arow) * lda + ak));
  uint4 bC;
  {
    float4 v0 = *reinterpret_cast<const float4*>(wrow + bk);
    float4 v1 = *reinterpret_cast<const float4*>(wrow + bk + 4);
    bC = packA8(v0, v1);
  }
  for (int k0 = 0; k0 < K; k0 += 32) {
    __syncthreads();
    *reinterpret_cast<uint2*>(&As[arow][ak]) = aC;
    if (nOk) *reinterpret_cast<uint4*>(&Bs[bn][bk]) = bC;
    else { uint4 z; z.x = z.y = z.z = z.w = 0; *reinterpret_cast<uint4*>(&Bs[bn][bk]) = z; }
    if (k0 + 32 < K) {
      aC = packA(*reinterpret_cast<const float4*>(A + (size_t)(r0 + arow) * lda + k0 + 32 + ak));
      float4 v0 = *reinterpret_cast<const float4*>(wrow + k0 + 32 + bk);
      float4 v1 = *reinterpret_cast<const float4*>(wrow + k0 + 32 + bk + 4);
      bC = packA8(v0, v1);
    }
    __syncthreads();
    bf16x8 afr = *reinterpret_cast<const bf16x8*>(&As[wr * 16 + (lane & 15)][(lane >> 4) * 8]);
#pragma unroll
    for (int j = 0; j < 2; ++j) {
      bf16x8 bfr = *reinterpret_cast<const bf16x8*>(&Bs[wc * 32 + j * 16 + (lane & 15)][(lane >> 4) * 8]);
      acc[j] = __builtin_amdgcn_mfma_f32_16x16x32_bf16(afr, bfr, acc[j], 0, 0, 0);
    }
  }
#pragma unroll
  for (int j = 0; j < 2; ++j)
#pragma unroll
    for (int rg = 0; rg < 4; ++rg) {
      int r = r0 + wr * 16 + ((lane >> 4) << 2) + rg;
      int c = c0 + wc * 32 + j * 16 + (lane & 15);
      if (c < N) C[(size_t)r * ldc + c] = acc[j][rg] + (bias ? bias[c] : 0.f);
    }
}

// ---------------------------------------------------------------------------
// Small elementwise kernels
// ---------------------------------------------------------------------------
__global__ void gather_hidden_k(const ushort_t* __restrict__ y0b,
                                const float* __restrict__ h1f,
                                const float* __restrict__ h1b,
                                float* __restrict__ hidden)
{
  int i = blockIdx.x * 256 + threadIdx.x;
  if (i >= BB * 4 * HDIM) return;
  int b = i >> 11, j = i & 2047;
  float v;
  if (j < 512)       v = b2f(y0b[(size_t)b * 131072 + 127 * 1024 + j]);
  else if (j < 1024) v = b2f(y0b[(size_t)b * 131072 + j]);
  else if (j < 1536) v = h1f[b * 512 + (j - 1024)];
  else               v = h1b[b * 512 + (j - 1536)];
  hidden[i] = v;
}

__global__ void z_k(const float* __restrict__ mu, const float* __restrict__ lv,
                    const float* __restrict__ eps, float* __restrict__ z,
                    float* __restrict__ out_mu, float* __restrict__ out_lv)
{
  int i = blockIdx.x * 256 + threadIdx.x;
  if (i >= BB * HDIM) return;
  float m = mu[i], l = lv[i];
  z[i] = eps[i] * expf(0.5f * l) + m;
  out_mu[i] = m;
  out_lv[i] = l;
}

__global__ void softmax_k(const float* __restrict__ logits,
                          float* __restrict__ out_sm,
                          float* __restrict__ out_lsm)
{
  int q = blockIdx.x;
  int lane = threadIdx.x;
  const float* row = logits + (size_t)q * 96;
  float v0 = row[lane];
  float v1 = (lane < 32) ? row[lane + 64] : -1e30f;
  float m = fmaxf(v0, v1);
#pragma unroll
  for (int o = 32; o; o >>= 1) m = fmaxf(m, __shfl_xor(m, o));
  float e0 = expf(v0 - m);
  float e1 = (lane < 32) ? expf(v1 - m) : 0.f;
  float s = e0 + e1;
#pragma unroll
  for (int o = 32; o; o >>= 1) s += __shfl_xor(s, o);
  float inv = 1.f / s, ls = logf(s);
  int b = (q >> 2) & 255;
  int t = (q >> 10) * 4 + (q & 3);
  size_t base = (size_t)b * TT * 96 + (size_t)t * 96;
  out_sm[base + lane]  = e0 * inv;
  out_lsm[base + lane] = v0 - m - ls;
  if (lane < 32) {
    out_sm[base + lane + 64]  = e1 * inv;
    out_lsm[base + lane + 64] = v1 - m - ls;
  }
}

__global__ void echo_k(const float* __restrict__ in, float* __restrict__ out)
{
  int i = blockIdx.x * 256 + threadIdx.x;
  if (i < BB * TT * NCC) out[i] = in[i];
}

// ---------------------------------------------------------------------------
extern "C" void kernel_launch(void* const* d_in, const int* in_sizes, int n_in,
                              void* d_out, int out_size, void* d_ws, size_t ws_size,
                              hipStream_t stream)
{
  const float* in        = (const float*)d_in[0];
  const float* eps       = (const float*)d_in[2];
  const float* enc0_Wih  = (const float*)d_in[3];
  const float* enc0_Whh  = (const float*)d_in[4];
  const float* enc0_bih  = (const float*)d_in[5];
  const float* enc0_bhh  = (const float*)d_in[6];
  const float* enc1_Wih  = (const float*)d_in[7];
  const float* enc1_Whh  = (const float*)d_in[8];
  const float* enc1_bih  = (const float*)d_in[9];
  const float* enc1_bhh  = (const float*)d_in[10];
  const float* con0_Wih  = (const float*)d_in[11];
  const float* con0_Whh  = (const float*)d_in[12];
  const float* con0_bih  = (const float*)d_in[13];
  const float* con0_bhh  = (const float*)d_in[14];
  const float* con1_Wih  = (const float*)d_in[15];
  const float* con1_Whh  = (const float*)d_in[16];
  const float* con1_bih  = (const float*)d_in[17];
  const float* con1_bhh  = (const float*)d_in[18];
  const float* dec0_Wih  = (const float*)d_in[19];
  const float* dec0_Whh  = (const float*)d_in[20];
  const float* dec0_bih  = (const float*)d_in[21];
  const float* dec0_bhh  = (const float*)d_in[22];
  const float* dec1_Wih  = (const float*)d_in[23];
  const float* dec1_Whh  = (const float*)d_in[24];
  const float* dec1_bih  = (const float*)d_in[25];
  const float* dec1_bhh  = (const float*)d_in[26];
  const float* W_mu      = (const float*)d_in[27];
  const float* b_mu      = (const float*)d_in[28];
  const float* W_lv      = (const float*)d_in[29];
  const float* b_lv      = (const float*)d_in[30];
  const float* W_ci      = (const float*)d_in[31];
  const float* b_ci      = (const float*)d_in[32];
  const float* W_ch      = (const float*)d_in[33];
  const float* b_ch      = (const float*)d_in[34];
  const float* W_out     = (const float*)d_in[35];
  const float* b_out     = (const float*)d_in[36];

  // ---- workspace layout (f32 slots; 33,554,432 = 128 MiB exactly) ----------
  float* ws = (float*)d_ws;
  ushort_t* y0b  = (ushort_t*)ws;                      // [256][128][1024] bf16
  float* e0pp    = ws + 16777216;                      // [2pp][2dir][256][512]
  ushort_t* gxF  = (ushort_t*)(ws + 17301504);         // [4096][1536] bf16
  ushort_t* gxB  = (ushort_t*)(ws + 20447232);
  // decoder-phase aliases (y0b/e0pp/gx dead):
  float* h0c   = ws;                                   // [32][256][512]
  float* h1c   = ws + 4194304;
  float* d0p[2] = { ws + 8388608,  ws + 12582912 };
  float* d1p[2] = { ws + 16777216, ws + 20971520 };
  // persistent smalls
  float* mu_f  = ws + 26492928;
  float* lv_f  = ws + 26624000;
  float* zz    = ws + 26755072;
  float* ci    = ws + 26886144;
  float* chv   = ws + 26910720;
  float* gx_c0 = ws + 27041792;
  ushort_t* Wb = (ushort_t*)(ws + 27435008);           // 12,238,848 bf16

  ushort_t* wb_e0_Wih = Wb;
  ushort_t* wb_e0_Whh = Wb + 294912;
  ushort_t* wb_e1_Wih = Wb + 1867776;
  ushort_t* wb_e1_Whh = Wb + 5013504;
  ushort_t* wb_c0_Whh = Wb + 6586368;
  ushort_t* wb_c1_Wih = Wb + 7372800;
  ushort_t* wb_c1_Whh = Wb + 8159232;
  ushort_t* wb_d0_Wih = Wb + 8945664;
  ushort_t* wb_d0_Whh = Wb + 9879552;
  ushort_t* wb_d1_Wih = Wb + 10665984;
  ushort_t* wb_d1_Whh = Wb + 11452416;

  float* outp   = (float*)d_out;
  float* out_sm = outp;
  float* out_ls = outp + 3145728;
  float* out_mu = outp + 6291456;
  float* out_lv = outp + 6422528;
  float* out_ec = outp + 6553600;
  // scratch in echo region (dead before echo_k)
  float* fscr = out_ec;
  float* h1f_pp[2] = { fscr,          fscr + 131072 };
  float* h1b_pp[2] = { fscr + 262144, fscr + 393216 };
  float* hidden    = fscr + 524288;                    // [256][2048]
  float* logits_q  = out_ec;                           // decoder: [8192 x 384]

  auto cvt = [&](const float* s, ushort_t* d, int n) {
    cvt_bf16_k<<<(n / 4 + 255) / 256, 256, 0, stream>>>(s, d, n / 4);
  };
  auto gemmM = [&](const float* A, int lda, const float* W, int ldw, const float* bias,
                   float* C, int ldc, int M, int N, int K) {
    mfma_gemm_k<<<dim3(M / 32, (N + 63) / 64), 256, 0, stream>>>(A, lda, W, ldw, bias, C, ldc, N, K);
  };
  auto gru1 = [&](const GruP& a, int rows) {
    GruP2 q; q.d[0] = a; q.d[1] = a;
    gru_k<<<dim3(rows / 32, 8, 1), 256, 0, stream>>>(q);
  };
  auto hstep2 = [&](const HP& a, const HP& b) {
    HP2 q; q.d[0] = a; q.d[1] = b;
    hstep_k<<<dim3(8, 8, 2), 256, 0, stream>>>(q);
  };
  auto hstep1 = [&](const HP& a) {
    HP2 q; q.d[0] = a; q.d[1] = a;
    hstep_k<<<dim3(8, 8, 1), 256, 0, stream>>>(q);
  };

  // ---------------- weight conversion ---------------------------------------
  cvt(enc0_Wih, wb_e0_Wih, 294912);
  cvt(enc0_Whh, wb_e0_Whh, 1572864);
  cvt(enc1_Wih, wb_e1_Wih, 3145728);
  cvt(enc1_Whh, wb_e1_Whh, 1572864);
  cvt(con0_Whh, wb_c0_Whh, 786432);
  cvt(con1_Wih, wb_c1_Wih, 786432);
  cvt(con1_Whh, wb_c1_Whh, 786432);
  cvt(dec0_Wih, wb_d0_Wih, 933888);
  cvt(dec0_Whh, wb_d0_Whh, 786432);
  cvt(dec1_Wih, wb_d1_Wih, 786432);
  cvt(dec1_Whh, wb_d1_Whh, 786432);

  // ---------------- encoder layer 0 (hstep, inline x-proj) -------------------
  for (int t = 0; t < TT; ++t) {
    int tr = 127 - t;
    HP f = {};
    f.hz = (t == 0);
    f.h_prev = e0pp + (size_t)((t + 1) & 1) * 262144;
    f.whh = wb_e0_Whh; f.bhh = enc0_bhh;
    f.x0 = in + (size_t)t * 96; f.x0s = 12288; f.w0 = wb_e0_Wih; f.k0n = 96;
    f.bih = enc0_bih;
    f.h_out = e0pp + (size_t)(t & 1) * 262144;
    f.y0o = y0b + (size_t)t * 1024; f.y0st = 131072;
    HP bd = {};
    bd.hz = (t == 0);
    bd.h_prev = e0pp + (size_t)((t + 1) & 1) * 262144 + 131072;
    bd.whh = wb_e0_Whh + 786432; bd.bhh = enc0_bhh + GG;
    bd.x0 = in + (size_t)tr * 96; bd.x0s = 12288; bd.w0 = wb_e0_Wih + 147456; bd.k0n = 96;
    bd.bih = enc0_bih + GG;
    bd.h_out = e0pp + (size_t)(t & 1) * 262144 + 131072;
    bd.y0o = y0b + (size_t)tr * 1024 + 512; bd.y0st = 131072;
    hstep2(f, bd);
  }

  // ---------------- encoder layer 1 (gx hoisted chunks + hstep) --------------
  for (int ch = 0; ch < 8; ++ch) {
    int t0 = ch * 16;
    gemm_chunk_k<<<dim3(128, 24), 256, 0, stream>>>(
        y0b + (size_t)t0 * 1024, 1024, wb_e1_Wih, enc1_bih, gxF);
    gemm_chunk_k<<<dim3(128, 24), 256, 0, stream>>>(
        y0b + (size_t)(127 - t0) * 1024, -1024, wb_e1_Wih + 1572864, enc1_bih + GG, gxB);
    for (int tl = 0; tl < 16; ++tl) {
      int t = t0 + tl;
      HP f = {};
      f.hz = (t == 0);
      f.h_prev = h1f_pp[(t + 1) & 1];
      f.whh = wb_e1_Whh; f.bhh = enc1_bhh;
      f.gxb = gxF; f.gxros = tl * 256;
      f.h_out = h1f_pp[t & 1];
      HP bd = {};
      bd.hz = (t == 0);
      bd.h_prev = h1b_pp[(t + 1) & 1];
      bd.whh = wb_e1_Whh + 786432; bd.bhh = enc1_bhh + GG;
      bd.gxb = gxB; bd.gxros = tl * 256;
      bd.h_out = h1b_pp[t & 1];
      hstep2(f, bd);
    }
  }

  // ---------------- latent ----------------------------------------------------
  gather_hidden_k<<<2048, 256, 0, stream>>>(y0b, h1f_pp[1], h1b_pp[1], hidden);
  gemmM(hidden, 2048, W_mu, 2048, b_mu, mu_f, 512, BB, 512, 2048);
  gemmM(hidden, 2048, W_lv, 2048, b_lv, lv_f, 512, BB, 512, 2048);
  z_k<<<512, 256, 0, stream>>>(mu_f, lv_f, eps, zz, out_mu, out_lv);
  gemmM(zz, 512, W_ci, 512, b_ci, ci, 96, BB, 96, 512);
  gemmM(zz, 512, W_ch, 512, b_ch, chv, 512, BB, 512, 512);
  gemmM(ci, 96, con0_Wih, 96, con0_bih, gx_c0, GG, BB, GG, 96);

  // ---------------- conductor (c0 via hstep, c1 via gru_k) -------------------
  for (int bar = 0; bar < NBB; ++bar) {
    HP c0 = {};
    c0.h_prev = (bar == 0) ? chv : h0c + (size_t)(bar - 1) * 131072;
    c0.whh = wb_c0_Whh; c0.bhh = con0_bhh;
    c0.gxf = gx_c0;
    c0.h_out = h0c + (size_t)bar * 131072;
    hstep1(c0);
    GruP c1 = {};
    c1.h_prev = (bar == 0) ? chv : h1c + (size_t)(bar - 1) * 131072; c1.hs = 512;
    c1.x0f = h0c + (size_t)bar * 131072; c1.x0s = 512;
    c1.W0 = wb_c1_Wih; c1.w0ld = 512; c1.K0 = 512;
    c1.Whh = wb_c1_Whh; c1.bih = con1_bih; c1.bhh = con1_bhh;
    c1.h_out = h1c + (size_t)bar * 131072; c1.os = 512;
    gru1(c1, BB);
  }

  // ---------------- decoder: 8192 rows, 4 steps -------------------------------
  const int R = NBB * BB;
  for (int s = 0; s < CPBB; ++s) {
    GruP d0 = {};
    d0.h_prev = (s == 0) ? h0c : d0p[(s - 1) & 1]; d0.hs = 512;
    d0.x0f = h1c; d0.x0s = 512; d0.W0 = wb_d0_Wih; d0.w0ld = 608; d0.K0 = 512;
    d0.x1f = in; d0.x1sp = s; d0.W1 = wb_d0_Wih + 512; d0.w1ld = 608; d0.K1 = 96;
    d0.Whh = wb_d0_Whh; d0.bih = dec0_bih; d0.bhh = dec0_bhh;
    d0.h_out = d0p[s & 1]; d0.os = 512;
    gru1(d0, R);
    GruP d1 = {};
    d1.h_prev = (s == 0) ? h1c : d1p[(s - 1) & 1]; d1.hs = 512;
    d1.x0f = d0p[s & 1]; d1.x0s = 512; d1.W0 = wb_d1_Wih; d1.w0ld = 512; d1.K0 = 512;
    d1.Whh = wb_d1_Whh; d1.bih = dec1_bih; d1.bhh = dec1_bhh;
    d1.h_out = d1p[s & 1]; d1.os = 512;
    gru1(d1, R);
    gemmM(d1p[s & 1], 512, W_out, 512, b_out, logits_q + (size_t)s * 96, 384, R, 96, 512);
  }

  // ---------------- softmax + echo --------------------------------------------
  softmax_k<<<NBB * BB * CPBB, 64, 0, stream>>>(logits_q, out_sm, out_ls);
  echo_k<<<12288, 256, 0, stream>>>(in, out_ec);
}